// Round 7
// baseline (420.229 us; speedup 1.0000x reference)
//
#include <hip/hip_runtime.h>
#include <math.h>

// Problem constants
#define BSZ 64
#define NPTS 512
#define DIM 256
#define MROWS 32768      // BSZ*NPTS
#define TOTROWS 65536
#define BIGF 1.0e9f

typedef __bf16 bf16x8 __attribute__((ext_vector_type(8)));
typedef float  f32x4  __attribute__((ext_vector_type(4)));

// ws layout (float offsets)
#define KB_OFF    0ull          // 8388608 floats as ushort[16777216]: Ybf1 -> Ybf2 -> K(bf16)
#define X_OFF     8388608ull    // 8388608 floats as ushort[16777216]: Xbf -> Ebf
#define H_OFF     16777216ull   // 8388608 floats as ushort[16777216]: Hbf
#define NORM_OFF  25165824ull   // 65536 f32
#define U_OFF     25231360ull   // 32768 f32 (colsum staged here pre-sinkhorn)
#define V_OFF     25264128ull   // 32768 f32
#define ARGA_OFF  25296896ull   // 32768 int
#define ARGB_OFF  25329664ull   // 32768 int
#define ACC_OFF   25362432ull   // 512 f32
#define WT1_OFF   25362944ull   // 32768 floats as ushort[65536]
#define WT2_OFF   25395712ull   // 32768 floats as ushort[65536]

#define ACC_PA   0
#define ACC_IN   1     // 64 slots
#define ACC_SUP  65    // 256 slots
#define ACC_CNT  321

__device__ __forceinline__ float bf2f(unsigned short h) {
    return __uint_as_float(((unsigned int)h) << 16);
}
__device__ __forceinline__ unsigned short f2bf(float f) {
    unsigned int u = __float_as_uint(f);
    u = (u + 0x7FFFu + ((u >> 16) & 1u)) >> 16;
    return (unsigned short)u;
}

// re-entrant
__device__ __forceinline__ float block_reduce_256(float val) {
    __shared__ float sh[4];
    int lane = threadIdx.x & 63;
    int wv = threadIdx.x >> 6;
    __syncthreads();
#pragma unroll
    for (int off = 32; off > 0; off >>= 1) val += __shfl_down(val, off, 64);
    if (lane == 0) sh[wv] = val;
    __syncthreads();
    float r = 0.f;
    if (wv == 0 && lane < 4) r = sh[lane];
    if (wv == 0) {
        r += __shfl_down(r, 2, 64);
        r += __shfl_down(r, 1, 64);
    }
    return r;  // valid in thread 0
}

__device__ __forceinline__ void unpack8(uint4 w, float* k) {
    k[0] = __uint_as_float(w.x << 16);
    k[1] = __uint_as_float(w.x & 0xFFFF0000u);
    k[2] = __uint_as_float(w.y << 16);
    k[3] = __uint_as_float(w.y & 0xFFFF0000u);
    k[4] = __uint_as_float(w.z << 16);
    k[5] = __uint_as_float(w.z & 0xFFFF0000u);
    k[6] = __uint_as_float(w.w << 16);
    k[7] = __uint_as_float(w.w & 0xFFFF0000u);
}
__device__ __forceinline__ float dot8(const float* k, const float* vr) {
    float rs = k[0] * vr[0];
    rs = fmaf(k[1], vr[1], rs); rs = fmaf(k[2], vr[2], rs);
    rs = fmaf(k[3], vr[3], rs); rs = fmaf(k[4], vr[4], rs);
    rs = fmaf(k[5], vr[5], rs); rs = fmaf(k[6], vr[6], rs);
    return fmaf(k[7], vr[7], rs);
}

// Packed 4-row all-lanes reduce: rows A,B,C,D per-lane partials -> row sums,
// replicated within 16-lane groups: g0=A, g1=C, g2=B, g3=D. 10 DS ops for 4 rows.
__device__ __forceinline__ float packed_reduce4(float p0, float p1, float p2, float p3, int l) {
    p0 += __shfl_xor(p0, 32, 64);
    p1 += __shfl_xor(p1, 32, 64);
    p2 += __shfl_xor(p2, 32, 64);
    p3 += __shfl_xor(p3, 32, 64);
    float m1 = (l & 32) ? p1 : p0;
    float m2 = (l & 32) ? p3 : p2;
    m1 += __shfl_xor(m1, 16, 64);
    m2 += __shfl_xor(m2, 16, 64);
    float s = (l & 16) ? m2 : m1;
    s += __shfl_xor(s, 8, 64);
    s += __shfl_xor(s, 4, 64);
    s += __shfl_xor(s, 2, 64);
    s += __shfl_xor(s, 1, 64);
    return s;
}
__device__ __forceinline__ float bcast_lane(float x, int lane) {
    return __uint_as_float((unsigned)__builtin_amdgcn_readlane((int)__float_as_uint(x), lane));
}

__global__ void zero_acc_kernel(float* acc, float* colsum) {
    int t = blockIdx.x * 256 + threadIdx.x;   // grid 128*256 = 32768
    if (t < 512) acc[t] = 0.f;
    colsum[t] = 0.f;
}

__global__ __launch_bounds__(256) void argmax_pa_kernel(
    const float* __restrict__ la, const float* __restrict__ lb,
    const float* __restrict__ pa, int* __restrict__ argA, int* __restrict__ argB,
    float* __restrict__ acc) {
    int i = blockIdx.x * 256 + threadIdx.x;
    float4 a = *(const float4*)&la[(size_t)i * 4];
    float av[4] = {a.x, a.y, a.z, a.w};
    int ba = 0; float bv = av[0];
#pragma unroll
    for (int c = 1; c < 4; ++c) if (av[c] > bv) { bv = av[c]; ba = c; }
    argA[i] = ba;
    float4 b = *(const float4*)&lb[(size_t)i * 4];
    float bw[4] = {b.x, b.y, b.z, b.w};
    int bbi = 0; float bm = bw[0];
#pragma unroll
    for (int c = 1; c < 4; ++c) if (bw[c] > bm) { bm = bw[c]; bbi = c; }
    argB[i] = bbi;
    float p = pa[i];
#pragma unroll
    for (int off = 32; off > 0; off >>= 1) p += __shfl_down(p, off, 64);
    if ((threadIdx.x & 63) == 0) atomicAdd(&acc[ACC_PA], p);
}

// f32 -> bf16 bulk cast; grid 2048x256, 4 float4-groups/thread
__global__ __launch_bounds__(256) void cast_bf_kernel(
    const float* __restrict__ src, unsigned short* __restrict__ dst) {
    int tid = blockIdx.x * 256 + threadIdx.x;      // < 524288
#pragma unroll
    for (int k = 0; k < 4; ++k) {
        int i4 = tid + k * 524288;                 // < 2097152
        float4 v = *(const float4*)&src[(size_t)i4 * 4];
        ushort4 o;
        o.x = f2bf(v.x); o.y = f2bf(v.y); o.z = f2bf(v.z); o.w = f2bf(v.w);
        *(ushort4*)&dst[(size_t)i4 * 4] = o;
    }
}

// W[256][256] f32 -> Wt[n][k] bf16 (transposed)
__global__ __launch_bounds__(256) void cast_wt_kernel(
    const float* __restrict__ W, unsigned short* __restrict__ Wt) {
    __shared__ float tile[16][17];
    int tx = threadIdx.x & 15, ty = threadIdx.x >> 4;
    int bx = blockIdx.x, by = blockIdx.y;
    tile[ty][tx] = W[(size_t)(by * 16 + ty) * 256 + bx * 16 + tx];
    __syncthreads();
    Wt[(size_t)(bx * 16 + ty) * 256 + by * 16 + tx] = f2bf(tile[tx][ty]);
}

// Y(bf16) = X(bf16, Mx256) @ W via Wt (bf16, transposed [n][k])
__global__ __launch_bounds__(256) void gemm_bf_kernel(
    const unsigned short* __restrict__ X, const unsigned short* __restrict__ Wt,
    unsigned short* __restrict__ Y) {
    __shared__ unsigned short Xs[64 * 40];
    __shared__ unsigned short Ws[256 * 40];
    const int t = threadIdx.x;
    const int L = t & 63, wv = t >> 6;
    const int q = L >> 4, n = L & 15;
    const size_t row0 = (size_t)blockIdx.x * 64;
    f32x4 acc[16];
#pragma unroll
    for (int nt = 0; nt < 16; ++nt) acc[nt] = (f32x4){0.f, 0.f, 0.f, 0.f};

    for (int k0 = 0; k0 < 256; k0 += 32) {
        {
            int r = t >> 2, seg = t & 3;
            *(uint4*)&Xs[r * 40 + seg * 8] =
                *(const uint4*)&X[(row0 + r) * 256 + k0 + seg * 8];
#pragma unroll
            for (int it = 0; it < 4; ++it) {
                int nn = (t >> 2) + it * 64;
                *(uint4*)&Ws[nn * 40 + seg * 8] =
                    *(const uint4*)&Wt[(size_t)nn * 256 + k0 + seg * 8];
            }
        }
        __syncthreads();
        bf16x8 av = *(const bf16x8*)&Xs[(wv * 16 + n) * 40 + q * 8];
#pragma unroll
        for (int nt = 0; nt < 16; ++nt) {
            bf16x8 bv = *(const bf16x8*)&Ws[(nt * 16 + n) * 40 + q * 8];
            acc[nt] = __builtin_amdgcn_mfma_f32_16x16x32_bf16(av, bv, acc[nt], 0, 0, 0);
        }
        __syncthreads();
    }
#pragma unroll
    for (int nt = 0; nt < 16; ++nt)
#pragma unroll
        for (int r = 0; r < 4; ++r) {
            size_t row = row0 + wv * 16 + q * 4 + r;
            Y[row * 256 + nt * 16 + n] = f2bf(acc[nt][r]);
        }
}

// y_bf16_out = LN(leaky_relu(y_bf16_in + bias)) * g + be ; optional row sq-norms
__global__ __launch_bounds__(256) void ln_bf_kernel(
    const unsigned short* __restrict__ Yin, unsigned short* __restrict__ Yout,
    const float* __restrict__ bias, const float* __restrict__ gam,
    const float* __restrict__ bet, float* __restrict__ norms) {
    int lane = threadIdx.x & 63;
    int wv = threadIdx.x >> 6;
    size_t row = (size_t)blockIdx.x * 4 + wv;
    ushort4 y4 = *(const ushort4*)&Yin[row * 256 + lane * 4];
    float4 b4 = *(const float4*)&bias[lane * 4];
    float h[4] = {bf2f(y4.x) + b4.x, bf2f(y4.y) + b4.y, bf2f(y4.z) + b4.z, bf2f(y4.w) + b4.w};
#pragma unroll
    for (int e = 0; e < 4; ++e) h[e] = h[e] >= 0.f ? h[e] : 0.01f * h[e];
    float s = h[0] + h[1] + h[2] + h[3];
    float sq = h[0] * h[0] + h[1] * h[1] + h[2] * h[2] + h[3] * h[3];
#pragma unroll
    for (int off = 32; off > 0; off >>= 1) {
        s += __shfl_down(s, off, 64);
        sq += __shfl_down(sq, off, 64);
    }
    s = __shfl(s, 0, 64); sq = __shfl(sq, 0, 64);
    float mean = s * (1.f / 256.f);
    float var = fmaxf(sq * (1.f / 256.f) - mean * mean, 0.f);
    float inv = rsqrtf(var + 1e-5f);
    float4 g4 = *(const float4*)&gam[lane * 4];
    float4 e4 = *(const float4*)&bet[lane * 4];
    float gv[4] = {g4.x, g4.y, g4.z, g4.w};
    float ev[4] = {e4.x, e4.y, e4.z, e4.w};
    ushort4 o4; float nr = 0.f;
    {
        unsigned short ob[4];
#pragma unroll
        for (int e = 0; e < 4; ++e) {
            float o = (h[e] - mean) * inv * gv[e] + ev[e];
            ob[e] = f2bf(o);
            float orr = bf2f(ob[e]);
            nr += orr * orr;
        }
        o4.x = ob[0]; o4.y = ob[1]; o4.z = ob[2]; o4.w = ob[3];
    }
    *(ushort4*)&Yout[row * 256 + lane * 4] = o4;
    if (norms) {
#pragma unroll
        for (int off = 32; off > 0; off >>= 1) nr += __shfl_down(nr, off, 64);
        if (lane == 0) norms[row] = nr;
    }
}

// cdist via MFMA + in/out loss partial + K(bf16) = exp(-2*cost) + K column sums
// BK=128 double-half schedule: stage half0 -> bar -> issue half1 loads to regs
// -> compute half0 (no barriers) -> bar -> write half1 -> bar -> compute half1.
// 3 barriers per block instead of 16; 8 staging loads in flight per phase.
__global__ __launch_bounds__(256) void cost_mfma_kernel(
    const unsigned short* __restrict__ E, const float* __restrict__ norms,
    const int* __restrict__ argA, const int* __restrict__ argB,
    const float* __restrict__ pa, const float* __restrict__ pb,
    unsigned short* __restrict__ Kb16, float* __restrict__ acc,
    float* __restrict__ colsum) {
    __shared__ unsigned short As[4][64 * 40];   // 4 k-chunks of 32, stride-40 layout
    __shared__ unsigned short Bs[4][64 * 40];
    const int t = threadIdx.x;
    const int L = t & 63, wv = t >> 6;
    const int q = L >> 4, n = L & 15;
    const int b = blockIdx.z;
    const int i0 = blockIdx.y * 64, j0 = blockIdx.x * 64;
    const unsigned short* eA = E + (size_t)b * 512 * 256;
    const unsigned short* eB = E + (size_t)(32768 + b * 512) * 256;
    const int r = t >> 2, seg = t & 3;
    const unsigned short* rowA = &eA[(size_t)(i0 + r) * 256 + seg * 8];
    const unsigned short* rowB = &eB[(size_t)(j0 + r) * 256 + seg * 8];
    f32x4 dot[4];
#pragma unroll
    for (int nt = 0; nt < 4; ++nt) dot[nt] = (f32x4){0.f, 0.f, 0.f, 0.f};

    // stage half 0 (k = 0..127)
#pragma unroll
    for (int c = 0; c < 4; ++c) {
        *(uint4*)&As[c][r * 40 + seg * 8] = *(const uint4*)(rowA + c * 32);
        *(uint4*)&Bs[c][r * 40 + seg * 8] = *(const uint4*)(rowB + c * 32);
    }
    __syncthreads();
    // issue half-1 loads into registers (latency hides under half-0 compute)
    uint4 pA[4], pB[4];
#pragma unroll
    for (int c = 0; c < 4; ++c) {
        pA[c] = *(const uint4*)(rowA + 128 + c * 32);
        pB[c] = *(const uint4*)(rowB + 128 + c * 32);
    }
    // compute half 0 (barrier-free)
#pragma unroll
    for (int c = 0; c < 4; ++c) {
        bf16x8 av = *(const bf16x8*)&As[c][(wv * 16 + n) * 40 + q * 8];
#pragma unroll
        for (int nt = 0; nt < 4; ++nt) {
            bf16x8 bv = *(const bf16x8*)&Bs[c][(nt * 16 + n) * 40 + q * 8];
            dot[nt] = __builtin_amdgcn_mfma_f32_16x16x32_bf16(av, bv, dot[nt], 0, 0, 0);
        }
    }
    __syncthreads();
    // write half 1
#pragma unroll
    for (int c = 0; c < 4; ++c) {
        *(uint4*)&As[c][r * 40 + seg * 8] = pA[c];
        *(uint4*)&Bs[c][r * 40 + seg * 8] = pB[c];
    }
    __syncthreads();
    // compute half 1
#pragma unroll
    for (int c = 0; c < 4; ++c) {
        bf16x8 av = *(const bf16x8*)&As[c][(wv * 16 + n) * 40 + q * 8];
#pragma unroll
        for (int nt = 0; nt < 4; ++nt) {
            bf16x8 bv = *(const bf16x8*)&Bs[c][(nt * 16 + n) * 40 + q * 8];
            dot[nt] = __builtin_amdgcn_mfma_f32_16x16x32_bf16(av, bv, dot[nt], 0, 0, 0);
        }
    }

    int base_row = i0 + wv * 16 + q * 4;
    float nA[4], pAr[4]; int cA[4];
#pragma unroll
    for (int rr = 0; rr < 4; ++rr) {
        nA[rr] = norms[b * 512 + base_row + rr];
        pAr[rr] = pa[b * 512 + base_row + rr];
        cA[rr] = argA[b * 512 + base_row + rr];
    }
    float part = 0.f;
    float csnt[4];
#pragma unroll
    for (int nt = 0; nt < 4; ++nt) {
        int col = j0 + nt * 16 + n;
        float nB = norms[32768 + b * 512 + col];
        float pB = pb[b * 512 + col];
        int cB = argB[b * 512 + col];
        float cloc = 0.f;
#pragma unroll
        for (int rr = 0; rr < 4; ++rr) {
            float d2 = nA[rr] + nB - 2.f * dot[nt][rr];
            float c = sqrtf(fmaxf(d2, 0.f));
            float pm = pAr[rr] * pB;
            float cc = c + (BIGF - BIGF * pm);
            float sgn = (cA[rr] == cB) ? 1.f : -1.f;
            part += cc * sgn * pm;
            unsigned short kb = f2bf(expf(-2.f * cc));
            Kb16[((size_t)b * 512 + base_row + rr) * 512 + col] = kb;
            cloc += bf2f(kb);
        }
        csnt[nt] = cloc;
    }
    // column sums for sinkhorn's v1 = 1/colsum: reduce over q-groups, waves, row-tiles
    __shared__ float csh[4][64];
#pragma unroll
    for (int nt = 0; nt < 4; ++nt) {
        float sq = csnt[nt];
        sq += __shfl_xor(sq, 16, 64);
        sq += __shfl_xor(sq, 32, 64);
        if (L < 16) csh[wv][nt * 16 + L] = sq;
    }
    __syncthreads();
    if (t < 64)
        atomicAdd(&colsum[(size_t)b * 512 + j0 + t],
                  csh[0][t] + csh[1][t] + csh[2][t] + csh[3][t]);
    float tot = block_reduce_256(part);
    if (threadIdx.x == 0) atomicAdd(&acc[ACC_IN + b], tot);
}

// Fused Sinkhorn, packed reduces. One block per batch, wave owns 32 rows,
// lane l owns cols l*8..+7. v1 = 1/colsum (from cost kernel, staged in u buf).
// 9 fused passes (u(t) row-reduce + col partials for v(t+1)) + 1 final row pass.
// Row reduce: 4 rows jointly in 10 DS ops (vs 24); broadcast via v_readlane (VALU).
__global__ __launch_bounds__(1024) void sinkhorn_kernel(
    const unsigned short* __restrict__ Kb16, float* u, float* __restrict__ v) {
    const int b = blockIdx.x;
    const unsigned short* Kb = Kb16 + (size_t)b * 262144;
    __shared__ float vv[512];
    __shared__ float cp[16][512];
    const int t = threadIdx.x, wv = t >> 6, l = t & 63;
    const unsigned short* base = Kb + (size_t)(wv * 32) * 512 + l * 8;

    // v1_j = (1/512) / (colsum_j/512) = 1/colsum_j  (u buffer holds colsum here)
    if (t < 512) vv[t] = 1.f / u[(size_t)b * 512 + t];
    __syncthreads();

    for (int it = 1; it <= 9; ++it) {
        float vr[8];
        *(f32x4*)&vr[0] = *(const f32x4*)&vv[l * 8];
        *(f32x4*)&vr[4] = *(const f32x4*)&vv[l * 8 + 4];
        float cs[8];
#pragma unroll
        for (int e = 0; e < 8; ++e) cs[e] = 0.f;
#pragma unroll 2
        for (int g = 0; g < 8; ++g) {
            const unsigned short* gb = base + (size_t)(g * 4) * 512;
            uint4 w0 = *(const uint4*)(gb);
            uint4 w1 = *(const uint4*)(gb + 512);
            uint4 w2 = *(const uint4*)(gb + 1024);
            uint4 w3 = *(const uint4*)(gb + 1536);
            float k0[8], k1[8], k2[8], k3[8];
            unpack8(w0, k0); unpack8(w1, k1); unpack8(w2, k2); unpack8(w3, k3);
            float p0 = dot8(k0, vr);
            float p1 = dot8(k1, vr);
            float p2 = dot8(k2, vr);
            float p3 = dot8(k3, vr);
            float s = packed_reduce4(p0, p1, p2, p3, l);
            float us = 0.001953125f * __builtin_amdgcn_rcpf(s);
            float uA = bcast_lane(us, 0);
            float uC = bcast_lane(us, 16);
            float uB = bcast_lane(us, 32);
            float uD = bcast_lane(us, 48);
#pragma unroll
            for (int e = 0; e < 8; ++e) {
                float c = fmaf(k0[e], uA, cs[e]);
                c = fmaf(k1[e], uB, c);
                c = fmaf(k2[e], uC, c);
                cs[e] = fmaf(k3[e], uD, c);
            }
        }
        *(f32x4*)&cp[wv][l * 8]     = *(f32x4*)&cs[0];
        *(f32x4*)&cp[wv][l * 8 + 4] = *(f32x4*)&cs[4];
        __syncthreads();
        if (t < 512) {
            float ss = 0.f;
#pragma unroll
            for (int k = 0; k < 16; ++k) ss += cp[k][t];
            vv[t] = (1.f / 512.f) / ss;
        }
        __syncthreads();
    }

    // final pass: u(10) from v(10), exact divide, direct global write
    {
        float vr[8];
        *(f32x4*)&vr[0] = *(const f32x4*)&vv[l * 8];
        *(f32x4*)&vr[4] = *(const f32x4*)&vv[l * 8 + 4];
#pragma unroll 2
        for (int g = 0; g < 8; ++g) {
            const unsigned short* gb = base + (size_t)(g * 4) * 512;
            uint4 w0 = *(const uint4*)(gb);
            uint4 w1 = *(const uint4*)(gb + 512);
            uint4 w2 = *(const uint4*)(gb + 1024);
            uint4 w3 = *(const uint4*)(gb + 1536);
            float k0[8], k1[8], k2[8], k3[8];
            unpack8(w0, k0); unpack8(w1, k1); unpack8(w2, k2); unpack8(w3, k3);
            float p0 = dot8(k0, vr);
            float p1 = dot8(k1, vr);
            float p2 = dot8(k2, vr);
            float p3 = dot8(k3, vr);
            float s = packed_reduce4(p0, p1, p2, p3, l);
            if ((l & 15) == 0) {
                int g16 = l >> 4;
                int rof = ((g16 & 1) << 1) | (g16 >> 1);   // 0,2,1,3
                u[(size_t)b * 512 + wv * 32 + g * 4 + rof] = 0.001953125f / s;
            }
        }
    }
    if (t < 512) v[(size_t)b * 512 + t] = vv[t];
}

// sup loss on bf16 K
__global__ __launch_bounds__(256) void sup_kernel(
    const unsigned short* __restrict__ Kb16, const float* __restrict__ u,
    const float* __restrict__ v, const float* __restrict__ rel,
    const float* __restrict__ pa, float* __restrict__ acc) {
    const int nthreads = 4096 * 256;
    int tid = blockIdx.x * 256 + threadIdx.x;
    float part = 0.f;
#pragma unroll
    for (int k = 0; k < 4; ++k) {
        int i4 = tid + k * nthreads;
        int e = i4 * 4;
        int b = e >> 18;
        int i = (e >> 9) & 511;
        int j0 = e & 511;
        ushort4 K4 = *(const ushort4*)&Kb16[(size_t)i4 * 4];
        float4 r4 = *(const float4*)&rel[(size_t)i4 * 4];
        float4 v4 = *(const float4*)&v[b * 512 + j0];
        float ui = u[b * 512 + i] * 512.f;
        float pai = pa[b * 512 + i];
        float d0 = ui * bf2f(K4.x) * v4.x - r4.x;
        float d1 = ui * bf2f(K4.y) * v4.y - r4.y;
        float d2 = ui * bf2f(K4.z) * v4.z - r4.z;
        float d3 = ui * bf2f(K4.w) * v4.w - r4.w;
        part += (d0 * d0 + d1 * d1 + d2 * d2 + d3 * d3) * pai;
    }
    float tot = block_reduce_256(part);
    if (threadIdx.x == 0) atomicAdd(&acc[ACC_SUP + (blockIdx.x & 255)], tot);
}

__global__ __launch_bounds__(256) void final_kernel(const float* __restrict__ acc,
                                                    float* __restrict__ out) {
    int t = threadIdx.x;
    float vin = (t < 64) ? acc[ACC_IN + t] : 0.f;
    float sIn = block_reduce_256(vin);
    float vsup = acc[ACC_SUP + t];
    float sSup = block_reduce_256(vsup);
    if (t == 0)
        out[0] = sIn * (1.f / 16777216.f) + 10.f * sSup / acc[ACC_PA];
}

extern "C" void kernel_launch(void* const* d_in, const int* in_sizes, int n_in,
                              void* d_out, int out_size, void* d_ws, size_t ws_size,
                              hipStream_t stream) {
    const float* la  = (const float*)d_in[0];
    const float* lb  = (const float*)d_in[1];
    const float* xA  = (const float*)d_in[2];
    const float* xB  = (const float*)d_in[3];
    const float* rel = (const float*)d_in[4];
    const float* pa  = (const float*)d_in[5];
    const float* pb  = (const float*)d_in[6];
    const float* W1  = (const float*)d_in[7];
    const float* b1  = (const float*)d_in[8];
    const float* g1  = (const float*)d_in[9];
    const float* be1 = (const float*)d_in[10];
    const float* W2  = (const float*)d_in[11];
    const float* b2  = (const float*)d_in[12];
    const float* g2  = (const float*)d_in[13];
    const float* be2 = (const float*)d_in[14];
    float* out = (float*)d_out;

    float* ws = (float*)d_ws;
    unsigned short* Kb16 = (unsigned short*)(ws + KB_OFF);   // Ybf1/Ybf2 then K
    unsigned short* Xbf  = (unsigned short*)(ws + X_OFF);    // Xbf then Ebf
    unsigned short* Hbf  = (unsigned short*)(ws + H_OFF);
    float* norms = ws + NORM_OFF;
    float* u     = ws + U_OFF;    // colsum staging, then u output
    float* v     = ws + V_OFF;
    int* argA    = (int*)(ws + ARGA_OFF);
    int* argB    = (int*)(ws + ARGB_OFF);
    float* acc   = ws + ACC_OFF;
    unsigned short* Wt1 = (unsigned short*)(ws + WT1_OFF);
    unsigned short* Wt2 = (unsigned short*)(ws + WT2_OFF);

    zero_acc_kernel<<<128, 256, 0, stream>>>(acc, u);        // zero acc + colsum
    argmax_pa_kernel<<<128, 256, 0, stream>>>(la, lb, pa, argA, argB, acc);

    // casts
    cast_bf_kernel<<<2048, 256, 0, stream>>>(xA, Xbf);
    cast_bf_kernel<<<2048, 256, 0, stream>>>(xB, Xbf + (size_t)MROWS * DIM);
    cast_wt_kernel<<<dim3(16, 16), 256, 0, stream>>>(W1, Wt1);
    cast_wt_kernel<<<dim3(16, 16), 256, 0, stream>>>(W2, Wt2);

    // layer 1
    gemm_bf_kernel<<<1024, 256, 0, stream>>>(Xbf, Wt1, Kb16);
    ln_bf_kernel<<<16384, 256, 0, stream>>>(Kb16, Hbf, b1, g1, be1, nullptr);
    // layer 2
    gemm_bf_kernel<<<1024, 256, 0, stream>>>(Hbf, Wt2, Kb16);
    ln_bf_kernel<<<16384, 256, 0, stream>>>(Kb16, Xbf, b2, g2, be2, norms);  // Ebf -> Xbf buf

    // cost + K (bf16) + column sums
    cost_mfma_kernel<<<dim3(8, 8, 64), 256, 0, stream>>>(Xbf, norms, argA, argB, pa, pb,
                                                         Kb16, acc, u);

    // sinkhorn: 10 K-passes (pass-0 folded into cost via colsum)
    sinkhorn_kernel<<<64, 1024, 0, stream>>>(Kb16, u, v);

    sup_kernel<<<4096, 256, 0, stream>>>(Kb16, u, v, rel, pa, acc);
    final_kernel<<<1, 256, 0, stream>>>(acc, out);
}

// Round 8
// 401.881 us; speedup vs baseline: 1.0457x; 1.0457x over previous
//
#include <hip/hip_runtime.h>
#include <math.h>

// Problem constants
#define BSZ 64
#define NPTS 512
#define DIM 256
#define MROWS 32768      // BSZ*NPTS
#define TOTROWS 65536
#define BIGF 1.0e9f

typedef __bf16 bf16x8 __attribute__((ext_vector_type(8)));
typedef float  f32x4  __attribute__((ext_vector_type(4)));
typedef __attribute__((address_space(1))) const void* as1cv;
typedef __attribute__((address_space(3))) void* as3v;

// ws layout (float offsets)
#define KB_OFF    0ull          // 8388608 floats as ushort[16777216]: Ybf1 -> Ybf2 -> K(bf16)
#define X_OFF     8388608ull    // 8388608 floats as ushort[16777216]: Xbf -> Ebf
#define H_OFF     16777216ull   // 8388608 floats as ushort[16777216]: Hbf
#define NORM_OFF  25165824ull   // 65536 f32
#define U_OFF     25231360ull   // 32768 f32 (colsum staged here pre-sinkhorn)
#define V_OFF     25264128ull   // 32768 f32
#define ARGA_OFF  25296896ull   // 32768 int
#define ARGB_OFF  25329664ull   // 32768 int
#define ACC_OFF   25362432ull   // 512 f32
#define WT1_OFF   25362944ull   // 32768 floats as ushort[65536]
#define WT2_OFF   25395712ull   // 32768 floats as ushort[65536]

#define ACC_PA   0
#define ACC_IN   1     // 64 slots
#define ACC_SUP  65    // 256 slots
#define ACC_CNT  321

__device__ __forceinline__ float bf2f(unsigned short h) {
    return __uint_as_float(((unsigned int)h) << 16);
}
__device__ __forceinline__ unsigned short f2bf(float f) {
    unsigned int u = __float_as_uint(f);
    u = (u + 0x7FFFu + ((u >> 16) & 1u)) >> 16;
    return (unsigned short)u;
}

// re-entrant
__device__ __forceinline__ float block_reduce_256(float val) {
    __shared__ float sh[4];
    int lane = threadIdx.x & 63;
    int wv = threadIdx.x >> 6;
    __syncthreads();
#pragma unroll
    for (int off = 32; off > 0; off >>= 1) val += __shfl_down(val, off, 64);
    if (lane == 0) sh[wv] = val;
    __syncthreads();
    float r = 0.f;
    if (wv == 0 && lane < 4) r = sh[lane];
    if (wv == 0) {
        r += __shfl_down(r, 2, 64);
        r += __shfl_down(r, 1, 64);
    }
    return r;  // valid in thread 0
}

__device__ __forceinline__ void unpack8(uint4 w, float* k) {
    k[0] = __uint_as_float(w.x << 16);
    k[1] = __uint_as_float(w.x & 0xFFFF0000u);
    k[2] = __uint_as_float(w.y << 16);
    k[3] = __uint_as_float(w.y & 0xFFFF0000u);
    k[4] = __uint_as_float(w.z << 16);
    k[5] = __uint_as_float(w.z & 0xFFFF0000u);
    k[6] = __uint_as_float(w.w << 16);
    k[7] = __uint_as_float(w.w & 0xFFFF0000u);
}
__device__ __forceinline__ float dot8(const float* k, const float* vr) {
    float rs = k[0] * vr[0];
    rs = fmaf(k[1], vr[1], rs); rs = fmaf(k[2], vr[2], rs);
    rs = fmaf(k[3], vr[3], rs); rs = fmaf(k[4], vr[4], rs);
    rs = fmaf(k[5], vr[5], rs); rs = fmaf(k[6], vr[6], rs);
    return fmaf(k[7], vr[7], rs);
}

// Packed 4-row all-lanes reduce: rows A,B,C,D per-lane partials -> row sums,
// replicated within 16-lane groups: g0=A, g1=C, g2=B, g3=D. 10 DS ops for 4 rows.
__device__ __forceinline__ float packed_reduce4(float p0, float p1, float p2, float p3, int l) {
    p0 += __shfl_xor(p0, 32, 64);
    p1 += __shfl_xor(p1, 32, 64);
    p2 += __shfl_xor(p2, 32, 64);
    p3 += __shfl_xor(p3, 32, 64);
    float m1 = (l & 32) ? p1 : p0;
    float m2 = (l & 32) ? p3 : p2;
    m1 += __shfl_xor(m1, 16, 64);
    m2 += __shfl_xor(m2, 16, 64);
    float s = (l & 16) ? m2 : m1;
    s += __shfl_xor(s, 8, 64);
    s += __shfl_xor(s, 4, 64);
    s += __shfl_xor(s, 2, 64);
    s += __shfl_xor(s, 1, 64);
    return s;
}
__device__ __forceinline__ float bcast_lane(float x, int lane) {
    return __uint_as_float((unsigned)__builtin_amdgcn_readlane((int)__float_as_uint(x), lane));
}

__global__ void zero_acc_kernel(float* acc, float* colsum) {
    int t = blockIdx.x * 256 + threadIdx.x;   // grid 128*256 = 32768
    if (t < 512) acc[t] = 0.f;
    colsum[t] = 0.f;
}

__global__ __launch_bounds__(256) void argmax_pa_kernel(
    const float* __restrict__ la, const float* __restrict__ lb,
    const float* __restrict__ pa, int* __restrict__ argA, int* __restrict__ argB,
    float* __restrict__ acc) {
    int i = blockIdx.x * 256 + threadIdx.x;
    float4 a = *(const float4*)&la[(size_t)i * 4];
    float av[4] = {a.x, a.y, a.z, a.w};
    int ba = 0; float bv = av[0];
#pragma unroll
    for (int c = 1; c < 4; ++c) if (av[c] > bv) { bv = av[c]; ba = c; }
    argA[i] = ba;
    float4 b = *(const float4*)&lb[(size_t)i * 4];
    float bw[4] = {b.x, b.y, b.z, b.w};
    int bbi = 0; float bm = bw[0];
#pragma unroll
    for (int c = 1; c < 4; ++c) if (bw[c] > bm) { bm = bw[c]; bbi = c; }
    argB[i] = bbi;
    float p = pa[i];
#pragma unroll
    for (int off = 32; off > 0; off >>= 1) p += __shfl_down(p, off, 64);
    if ((threadIdx.x & 63) == 0) atomicAdd(&acc[ACC_PA], p);
}

// f32 -> bf16 bulk cast; grid 2048x256, 4 float4-groups/thread
__global__ __launch_bounds__(256) void cast_bf_kernel(
    const float* __restrict__ src, unsigned short* __restrict__ dst) {
    int tid = blockIdx.x * 256 + threadIdx.x;      // < 524288
#pragma unroll
    for (int k = 0; k < 4; ++k) {
        int i4 = tid + k * 524288;                 // < 2097152
        float4 v = *(const float4*)&src[(size_t)i4 * 4];
        ushort4 o;
        o.x = f2bf(v.x); o.y = f2bf(v.y); o.z = f2bf(v.z); o.w = f2bf(v.w);
        *(ushort4*)&dst[(size_t)i4 * 4] = o;
    }
}

// W[256][256] f32 -> Wt[n][k] bf16 (transposed)
__global__ __launch_bounds__(256) void cast_wt_kernel(
    const float* __restrict__ W, unsigned short* __restrict__ Wt) {
    __shared__ float tile[16][17];
    int tx = threadIdx.x & 15, ty = threadIdx.x >> 4;
    int bx = blockIdx.x, by = blockIdx.y;
    tile[ty][tx] = W[(size_t)(by * 16 + ty) * 256 + bx * 16 + tx];
    __syncthreads();
    Wt[(size_t)(bx * 16 + ty) * 256 + by * 16 + tx] = f2bf(tile[tx][ty]);
}

// Y(bf16) = X(bf16, Mx256) @ W via Wt (bf16, transposed [n][k])
__global__ __launch_bounds__(256) void gemm_bf_kernel(
    const unsigned short* __restrict__ X, const unsigned short* __restrict__ Wt,
    unsigned short* __restrict__ Y) {
    __shared__ unsigned short Xs[64 * 40];
    __shared__ unsigned short Ws[256 * 40];
    const int t = threadIdx.x;
    const int L = t & 63, wv = t >> 6;
    const int q = L >> 4, n = L & 15;
    const size_t row0 = (size_t)blockIdx.x * 64;
    f32x4 acc[16];
#pragma unroll
    for (int nt = 0; nt < 16; ++nt) acc[nt] = (f32x4){0.f, 0.f, 0.f, 0.f};

    for (int k0 = 0; k0 < 256; k0 += 32) {
        {
            int r = t >> 2, seg = t & 3;
            *(uint4*)&Xs[r * 40 + seg * 8] =
                *(const uint4*)&X[(row0 + r) * 256 + k0 + seg * 8];
#pragma unroll
            for (int it = 0; it < 4; ++it) {
                int nn = (t >> 2) + it * 64;
                *(uint4*)&Ws[nn * 40 + seg * 8] =
                    *(const uint4*)&Wt[(size_t)nn * 256 + k0 + seg * 8];
            }
        }
        __syncthreads();
        bf16x8 av = *(const bf16x8*)&Xs[(wv * 16 + n) * 40 + q * 8];
#pragma unroll
        for (int nt = 0; nt < 16; ++nt) {
            bf16x8 bv = *(const bf16x8*)&Ws[(nt * 16 + n) * 40 + q * 8];
            acc[nt] = __builtin_amdgcn_mfma_f32_16x16x32_bf16(av, bv, acc[nt], 0, 0, 0);
        }
        __syncthreads();
    }
#pragma unroll
    for (int nt = 0; nt < 16; ++nt)
#pragma unroll
        for (int r = 0; r < 4; ++r) {
            size_t row = row0 + wv * 16 + q * 4 + r;
            Y[row * 256 + nt * 16 + n] = f2bf(acc[nt][r]);
        }
}

// y_bf16_out = LN(leaky_relu(y_bf16_in + bias)) * g + be ; optional row sq-norms
__global__ __launch_bounds__(256) void ln_bf_kernel(
    const unsigned short* __restrict__ Yin, unsigned short* __restrict__ Yout,
    const float* __restrict__ bias, const float* __restrict__ gam,
    const float* __restrict__ bet, float* __restrict__ norms) {
    int lane = threadIdx.x & 63;
    int wv = threadIdx.x >> 6;
    size_t row = (size_t)blockIdx.x * 4 + wv;
    ushort4 y4 = *(const ushort4*)&Yin[row * 256 + lane * 4];
    float4 b4 = *(const float4*)&bias[lane * 4];
    float h[4] = {bf2f(y4.x) + b4.x, bf2f(y4.y) + b4.y, bf2f(y4.z) + b4.z, bf2f(y4.w) + b4.w};
#pragma unroll
    for (int e = 0; e < 4; ++e) h[e] = h[e] >= 0.f ? h[e] : 0.01f * h[e];
    float s = h[0] + h[1] + h[2] + h[3];
    float sq = h[0] * h[0] + h[1] * h[1] + h[2] * h[2] + h[3] * h[3];
#pragma unroll
    for (int off = 32; off > 0; off >>= 1) {
        s += __shfl_down(s, off, 64);
        sq += __shfl_down(sq, off, 64);
    }
    s = __shfl(s, 0, 64); sq = __shfl(sq, 0, 64);
    float mean = s * (1.f / 256.f);
    float var = fmaxf(sq * (1.f / 256.f) - mean * mean, 0.f);
    float inv = rsqrtf(var + 1e-5f);
    float4 g4 = *(const float4*)&gam[lane * 4];
    float4 e4 = *(const float4*)&bet[lane * 4];
    float gv[4] = {g4.x, g4.y, g4.z, g4.w};
    float ev[4] = {e4.x, e4.y, e4.z, e4.w};
    ushort4 o4; float nr = 0.f;
    {
        unsigned short ob[4];
#pragma unroll
        for (int e = 0; e < 4; ++e) {
            float o = (h[e] - mean) * inv * gv[e] + ev[e];
            ob[e] = f2bf(o);
            float orr = bf2f(ob[e]);
            nr += orr * orr;
        }
        o4.x = ob[0]; o4.y = ob[1]; o4.z = ob[2]; o4.w = ob[3];
    }
    *(ushort4*)&Yout[row * 256 + lane * 4] = o4;
    if (norms) {
#pragma unroll
        for (int off = 32; off > 0; off >>= 1) nr += __shfl_down(nr, off, 64);
        if (lane == 0) norms[row] = nr;
    }
}

// cdist via MFMA + in/out loss partial + K(bf16) = exp(-2*cost) + K column sums.
// Full-tile staging via global_load_lds (no VGPR round-trip, no scratch):
// linear LDS rows (512B) with seg XOR-swizzle, inverse-swizzled per-lane global
// source (rule: both-sides-or-neither). ONE staging barrier; 32 MFMAs barrier-free.
// Epilogue reductions reuse As space after a barrier (total 3 barriers vs 16).
__global__ __launch_bounds__(256) void cost_mfma_kernel(
    const unsigned short* __restrict__ E, const float* __restrict__ norms,
    const int* __restrict__ argA, const int* __restrict__ argB,
    const float* __restrict__ pa, const float* __restrict__ pb,
    unsigned short* __restrict__ Kb16, float* __restrict__ acc,
    float* __restrict__ colsum) {
    __shared__ unsigned short As[64 * 256];   // 32 KB, row stride 512B, seg-swizzled
    __shared__ unsigned short Bs[64 * 256];   // 32 KB  (total exactly 64 KB)
    const int t = threadIdx.x;
    const int L = t & 63, wv = t >> 6;
    const int q = L >> 4, n = L & 15;
    const int b = blockIdx.z;
    const int i0 = blockIdx.y * 64, j0 = blockIdx.x * 64;
    const unsigned short* eA = E + (size_t)b * 512 * 256;
    const unsigned short* eB = E + (size_t)(32768 + b * 512) * 256;

    // stage: wave w covers rows w*16..w*16+15; each instr moves 2 rows (1 KB).
    // LDS[row][seg'] = global[row][seg' ^ (row&7)]  (seg = 16B unit)
    {
        const int lrow = L >> 5;          // row within the 2-row pair
        const int segp = L & 31;          // destination segment
#pragma unroll
        for (int j = 0; j < 8; ++j) {
            int row = wv * 16 + 2 * j + lrow;
            int sseg = segp ^ (row & 7);
            const unsigned short* ga = &eA[(size_t)(i0 + row) * 256 + sseg * 8];
            const unsigned short* gb = &eB[(size_t)(j0 + row) * 256 + sseg * 8];
            __builtin_amdgcn_global_load_lds((as1cv)ga, (as3v)&As[(wv * 16 + 2 * j) * 256],
                                             16, 0, 0);
            __builtin_amdgcn_global_load_lds((as1cv)gb, (as3v)&Bs[(wv * 16 + 2 * j) * 256],
                                             16, 0, 0);
        }
    }
    f32x4 dot[4];
#pragma unroll
    for (int nt = 0; nt < 4; ++nt) dot[nt] = (f32x4){0.f, 0.f, 0.f, 0.f};
    __syncthreads();   // single staging drain

    const int rowa = wv * 16 + n;
    const int sw = n & 7;                 // == rowa&7 == rowb&7
#pragma unroll
    for (int c = 0; c < 8; ++c) {
        bf16x8 av = *(const bf16x8*)&As[rowa * 256 + (((c * 4 + q) ^ sw) * 8)];
#pragma unroll
        for (int nt = 0; nt < 4; ++nt) {
            int rowb = nt * 16 + n;
            bf16x8 bv = *(const bf16x8*)&Bs[rowb * 256 + (((c * 4 + q) ^ sw) * 8)];
            dot[nt] = __builtin_amdgcn_mfma_f32_16x16x32_bf16(av, bv, dot[nt], 0, 0, 0);
        }
    }

    int base_row = i0 + wv * 16 + q * 4;
    float nA[4], pAr[4]; int cA[4];
#pragma unroll
    for (int rr = 0; rr < 4; ++rr) {
        nA[rr] = norms[b * 512 + base_row + rr];
        pAr[rr] = pa[b * 512 + base_row + rr];
        cA[rr] = argA[b * 512 + base_row + rr];
    }
    float part = 0.f;
    float csnt[4];
#pragma unroll
    for (int nt = 0; nt < 4; ++nt) {
        int col = j0 + nt * 16 + n;
        float nB = norms[32768 + b * 512 + col];
        float pB = pb[b * 512 + col];
        int cB = argB[b * 512 + col];
        float cloc = 0.f;
#pragma unroll
        for (int rr = 0; rr < 4; ++rr) {
            float d2 = nA[rr] + nB - 2.f * dot[nt][rr];
            float c = sqrtf(fmaxf(d2, 0.f));
            float pm = pAr[rr] * pB;
            float cc = c + (BIGF - BIGF * pm);
            float sgn = (cA[rr] == cB) ? 1.f : -1.f;
            part += cc * sgn * pm;
            unsigned short kb = f2bf(expf(-2.f * cc));
            Kb16[((size_t)b * 512 + base_row + rr) * 512 + col] = kb;
            cloc += bf2f(kb);
        }
        csnt[nt] = cloc;
    }
    // reductions: reuse As space (all tile reads complete after barrier)
    __syncthreads();
    float* red = (float*)As;   // [0..255]: per-wave col partials; [256..259]: loss partials
#pragma unroll
    for (int nt = 0; nt < 4; ++nt) {
        float sq2 = csnt[nt];
        sq2 += __shfl_xor(sq2, 16, 64);
        sq2 += __shfl_xor(sq2, 32, 64);
        if (L < 16) red[wv * 64 + nt * 16 + L] = sq2;
    }
    {
        float pw = part;
#pragma unroll
        for (int off = 32; off > 0; off >>= 1) pw += __shfl_down(pw, off, 64);
        if (L == 0) red[256 + wv] = pw;
    }
    __syncthreads();
    if (t < 64)
        atomicAdd(&colsum[(size_t)b * 512 + j0 + t],
                  red[t] + red[64 + t] + red[128 + t] + red[192 + t]);
    if (t == 0)
        atomicAdd(&acc[ACC_IN + b], red[256] + red[257] + red[258] + red[259]);
}

// Fused Sinkhorn, packed reduces. One block per batch, wave owns 32 rows,
// lane l owns cols l*8..+7. v1 = 1/colsum (from cost kernel, staged in u buf).
// 9 fused passes (u(t) row-reduce + col partials for v(t+1)) + 1 final row pass.
// Row reduce: 4 rows jointly in 10 DS ops (vs 24); broadcast via v_readlane (VALU).
__global__ __launch_bounds__(1024) void sinkhorn_kernel(
    const unsigned short* __restrict__ Kb16, float* u, float* __restrict__ v) {
    const int b = blockIdx.x;
    const unsigned short* Kb = Kb16 + (size_t)b * 262144;
    __shared__ float vv[512];
    __shared__ float cp[16][512];
    const int t = threadIdx.x, wv = t >> 6, l = t & 63;
    const unsigned short* base = Kb + (size_t)(wv * 32) * 512 + l * 8;

    // v1_j = (1/512) / (colsum_j/512) = 1/colsum_j  (u buffer holds colsum here)
    if (t < 512) vv[t] = 1.f / u[(size_t)b * 512 + t];
    __syncthreads();

    for (int it = 1; it <= 9; ++it) {
        float vr[8];
        *(f32x4*)&vr[0] = *(const f32x4*)&vv[l * 8];
        *(f32x4*)&vr[4] = *(const f32x4*)&vv[l * 8 + 4];
        float cs[8];
#pragma unroll
        for (int e = 0; e < 8; ++e) cs[e] = 0.f;
#pragma unroll 2
        for (int g = 0; g < 8; ++g) {
            const unsigned short* gb = base + (size_t)(g * 4) * 512;
            uint4 w0 = *(const uint4*)(gb);
            uint4 w1 = *(const uint4*)(gb + 512);
            uint4 w2 = *(const uint4*)(gb + 1024);
            uint4 w3 = *(const uint4*)(gb + 1536);
            float k0[8], k1[8], k2[8], k3[8];
            unpack8(w0, k0); unpack8(w1, k1); unpack8(w2, k2); unpack8(w3, k3);
            float p0 = dot8(k0, vr);
            float p1 = dot8(k1, vr);
            float p2 = dot8(k2, vr);
            float p3 = dot8(k3, vr);
            float s = packed_reduce4(p0, p1, p2, p3, l);
            float us = 0.001953125f * __builtin_amdgcn_rcpf(s);
            float uA = bcast_lane(us, 0);
            float uC = bcast_lane(us, 16);
            float uB = bcast_lane(us, 32);
            float uD = bcast_lane(us, 48);
#pragma unroll
            for (int e = 0; e < 8; ++e) {
                float c = fmaf(k0[e], uA, cs[e]);
                c = fmaf(k1[e], uB, c);
                c = fmaf(k2[e], uC, c);
                cs[e] = fmaf(k3[e], uD, c);
            }
        }
        *(f32x4*)&cp[wv][l * 8]     = *(f32x4*)&cs[0];
        *(f32x4*)&cp[wv][l * 8 + 4] = *(f32x4*)&cs[4];
        __syncthreads();
        if (t < 512) {
            float ss = 0.f;
#pragma unroll
            for (int k = 0; k < 16; ++k) ss += cp[k][t];
            vv[t] = (1.f / 512.f) / ss;
        }
        __syncthreads();
    }

    // final pass: u(10) from v(10), exact divide, direct global write
    {
        float vr[8];
        *(f32x4*)&vr[0] = *(const f32x4*)&vv[l * 8];
        *(f32x4*)&vr[4] = *(const f32x4*)&vv[l * 8 + 4];
#pragma unroll 2
        for (int g = 0; g < 8; ++g) {
            const unsigned short* gb = base + (size_t)(g * 4) * 512;
            uint4 w0 = *(const uint4*)(gb);
            uint4 w1 = *(const uint4*)(gb + 512);
            uint4 w2 = *(const uint4*)(gb + 1024);
            uint4 w3 = *(const uint4*)(gb + 1536);
            float k0[8], k1[8], k2[8], k3[8];
            unpack8(w0, k0); unpack8(w1, k1); unpack8(w2, k2); unpack8(w3, k3);
            float p0 = dot8(k0, vr);
            float p1 = dot8(k1, vr);
            float p2 = dot8(k2, vr);
            float p3 = dot8(k3, vr);
            float s = packed_reduce4(p0, p1, p2, p3, l);
            if ((l & 15) == 0) {
                int g16 = l >> 4;
                int rof = ((g16 & 1) << 1) | (g16 >> 1);   // 0,2,1,3
                u[(size_t)b * 512 + wv * 32 + g * 4 + rof] = 0.001953125f / s;
            }
        }
    }
    if (t < 512) v[(size_t)b * 512 + t] = vv[t];
}

// sup loss on bf16 K
__global__ __launch_bounds__(256) void sup_kernel(
    const unsigned short* __restrict__ Kb16, const float* __restrict__ u,
    const float* __restrict__ v, const float* __restrict__ rel,
    const float* __restrict__ pa, float* __restrict__ acc) {
    const int nthreads = 4096 * 256;
    int tid = blockIdx.x * 256 + threadIdx.x;
    float part = 0.f;
#pragma unroll
    for (int k = 0; k < 4; ++k) {
        int i4 = tid + k * nthreads;
        int e = i4 * 4;
        int b = e >> 18;
        int i = (e >> 9) & 511;
        int j0 = e & 511;
        ushort4 K4 = *(const ushort4*)&Kb16[(size_t)i4 * 4];
        float4 r4 = *(const float4*)&rel[(size_t)i4 * 4];
        float4 v4 = *(const float4*)&v[b * 512 + j0];
        float ui = u[b * 512 + i] * 512.f;
        float pai = pa[b * 512 + i];
        float d0 = ui * bf2f(K4.x) * v4.x - r4.x;
        float d1 = ui * bf2f(K4.y) * v4.y - r4.y;
        float d2 = ui * bf2f(K4.z) * v4.z - r4.z;
        float d3 = ui * bf2f(K4.w) * v4.w - r4.w;
        part += (d0 * d0 + d1 * d1 + d2 * d2 + d3 * d3) * pai;
    }
    float tot = block_reduce_256(part);
    if (threadIdx.x == 0) atomicAdd(&acc[ACC_SUP + (blockIdx.x & 255)], tot);
}

__global__ __launch_bounds__(256) void final_kernel(const float* __restrict__ acc,
                                                    float* __restrict__ out) {
    int t = threadIdx.x;
    float vin = (t < 64) ? acc[ACC_IN + t] : 0.f;
    float sIn = block_reduce_256(vin);
    float vsup = acc[ACC_SUP + t];
    float sSup = block_reduce_256(vsup);
    if (t == 0)
        out[0] = sIn * (1.f / 16777216.f) + 10.f * sSup / acc[ACC_PA];
}

extern "C" void kernel_launch(void* const* d_in, const int* in_sizes, int n_in,
                              void* d_out, int out_size, void* d_ws, size_t ws_size,
                              hipStream_t stream) {
    const float* la  = (const float*)d_in[0];
    const float* lb  = (const float*)d_in[1];
    const float* xA  = (const float*)d_in[2];
    const float* xB  = (const float*)d_in[3];
    const float* rel = (const float*)d_in[4];
    const float* pa  = (const float*)d_in[5];
    const float* pb  = (const float*)d_in[6];
    const float* W1  = (const float*)d_in[7];
    const float* b1  = (const float*)d_in[8];
    const float* g1  = (const float*)d_in[9];
    const float* be1 = (const float*)d_in[10];
    const float* W2  = (const float*)d_in[11];
    const float* b2  = (const float*)d_in[12];
    const float* g2  = (const float*)d_in[13];
    const float* be2 = (const float*)d_in[14];
    float* out = (float*)d_out;

    float* ws = (float*)d_ws;
    unsigned short* Kb16 = (unsigned short*)(ws + KB_OFF);   // Ybf1/Ybf2 then K
    unsigned short* Xbf  = (unsigned short*)(ws + X_OFF);    // Xbf then Ebf
    unsigned short* Hbf  = (unsigned short*)(ws + H_OFF);
    float* norms = ws + NORM_OFF;
    float* u     = ws + U_OFF;    // colsum staging, then u output
    float* v     = ws + V_OFF;
    int* argA    = (int*)(ws + ARGA_OFF);
    int* argB    = (int*)(ws + ARGB_OFF);
    float* acc   = ws + ACC_OFF;
    unsigned short* Wt1 = (unsigned short*)(ws + WT1_OFF);
    unsigned short* Wt2 = (unsigned short*)(ws + WT2_OFF);

    zero_acc_kernel<<<128, 256, 0, stream>>>(acc, u);        // zero acc + colsum
    argmax_pa_kernel<<<128, 256, 0, stream>>>(la, lb, pa, argA, argB, acc);

    // casts
    cast_bf_kernel<<<2048, 256, 0, stream>>>(xA, Xbf);
    cast_bf_kernel<<<2048, 256, 0, stream>>>(xB, Xbf + (size_t)MROWS * DIM);
    cast_wt_kernel<<<dim3(16, 16), 256, 0, stream>>>(W1, Wt1);
    cast_wt_kernel<<<dim3(16, 16), 256, 0, stream>>>(W2, Wt2);

    // layer 1
    gemm_bf_kernel<<<1024, 256, 0, stream>>>(Xbf, Wt1, Kb16);
    ln_bf_kernel<<<16384, 256, 0, stream>>>(Kb16, Hbf, b1, g1, be1, nullptr);
    // layer 2
    gemm_bf_kernel<<<1024, 256, 0, stream>>>(Hbf, Wt2, Kb16);
    ln_bf_kernel<<<16384, 256, 0, stream>>>(Kb16, Xbf, b2, g2, be2, norms);  // Ebf -> Xbf buf

    // cost + K (bf16) + column sums
    cost_mfma_kernel<<<dim3(8, 8, 64), 256, 0, stream>>>(Xbf, norms, argA, argB, pa, pb,
                                                         Kb16, acc, u);

    // sinkhorn: 10 K-passes (pass-0 folded into cost via colsum)
    sinkhorn_kernel<<<64, 1024, 0, stream>>>(Kb16, u, v);

    sup_kernel<<<4096, 256, 0, stream>>>(Kb16, u, v, rel, pa, acc);
    final_kernel<<<1, 256, 0, stream>>>(acc, out);
}

// Round 9
// 400.136 us; speedup vs baseline: 1.0502x; 1.0044x over previous
//
#include <hip/hip_runtime.h>
#include <math.h>

// Problem constants
#define BSZ 64
#define NPTS 512
#define DIM 256
#define MROWS 32768      // BSZ*NPTS
#define TOTROWS 65536
#define BIGF 1.0e9f

typedef __bf16 bf16x8 __attribute__((ext_vector_type(8)));
typedef float  f32x4  __attribute__((ext_vector_type(4)));
typedef __attribute__((address_space(1))) const void* as1cv;
typedef __attribute__((address_space(3))) void* as3v;

// ws layout (float offsets)
#define KB_OFF    0ull          // 8388608 floats as ushort[16777216]: Ybf1 -> Ybf2 -> K(bf16)
#define X_OFF     8388608ull    // 8388608 floats as ushort[16777216]: Xbf -> Ebf
#define H_OFF     16777216ull   // 8388608 floats as ushort[16777216]: Hbf
#define NORM_OFF  25165824ull   // 65536 f32
#define U_OFF     25231360ull   // 32768 f32 (colsum staged here pre-sinkhorn)
#define V_OFF     25264128ull   // 32768 f32
#define ARGA_OFF  25296896ull   // 32768 int
#define ARGB_OFF  25329664ull   // 32768 int
#define ACC_OFF   25362432ull   // 512 f32
#define WT1_OFF   25362944ull   // 32768 floats as ushort[65536]
#define WT2_OFF   25395712ull   // 32768 floats as ushort[65536]

#define ACC_PA   0
#define ACC_IN   1     // 64 slots
#define ACC_SUP  65    // 256 slots
#define ACC_CNT  321

__device__ __forceinline__ float bf2f(unsigned short h) {
    return __uint_as_float(((unsigned int)h) << 16);
}
__device__ __forceinline__ unsigned short f2bf(float f) {
    unsigned int u = __float_as_uint(f);
    u = (u + 0x7FFFu + ((u >> 16) & 1u)) >> 16;
    return (unsigned short)u;
}

// re-entrant
__device__ __forceinline__ float block_reduce_256(float val) {
    __shared__ float sh[4];
    int lane = threadIdx.x & 63;
    int wv = threadIdx.x >> 6;
    __syncthreads();
#pragma unroll
    for (int off = 32; off > 0; off >>= 1) val += __shfl_down(val, off, 64);
    if (lane == 0) sh[wv] = val;
    __syncthreads();
    float r = 0.f;
    if (wv == 0 && lane < 4) r = sh[lane];
    if (wv == 0) {
        r += __shfl_down(r, 2, 64);
        r += __shfl_down(r, 1, 64);
    }
    return r;  // valid in thread 0
}

__device__ __forceinline__ void unpack8(uint4 w, float* k) {
    k[0] = __uint_as_float(w.x << 16);
    k[1] = __uint_as_float(w.x & 0xFFFF0000u);
    k[2] = __uint_as_float(w.y << 16);
    k[3] = __uint_as_float(w.y & 0xFFFF0000u);
    k[4] = __uint_as_float(w.z << 16);
    k[5] = __uint_as_float(w.z & 0xFFFF0000u);
    k[6] = __uint_as_float(w.w << 16);
    k[7] = __uint_as_float(w.w & 0xFFFF0000u);
}
__device__ __forceinline__ float dot8(const float* k, const float* vr) {
    float rs = k[0] * vr[0];
    rs = fmaf(k[1], vr[1], rs); rs = fmaf(k[2], vr[2], rs);
    rs = fmaf(k[3], vr[3], rs); rs = fmaf(k[4], vr[4], rs);
    rs = fmaf(k[5], vr[5], rs); rs = fmaf(k[6], vr[6], rs);
    return fmaf(k[7], vr[7], rs);
}

// Packed 4-row all-lanes reduce: rows A,B,C,D per-lane partials -> row sums,
// replicated within 16-lane groups: g0=A, g1=C, g2=B, g3=D. 10 DS ops for 4 rows.
__device__ __forceinline__ float packed_reduce4(float p0, float p1, float p2, float p3, int l) {
    p0 += __shfl_xor(p0, 32, 64);
    p1 += __shfl_xor(p1, 32, 64);
    p2 += __shfl_xor(p2, 32, 64);
    p3 += __shfl_xor(p3, 32, 64);
    float m1 = (l & 32) ? p1 : p0;
    float m2 = (l & 32) ? p3 : p2;
    m1 += __shfl_xor(m1, 16, 64);
    m2 += __shfl_xor(m2, 16, 64);
    float s = (l & 16) ? m2 : m1;
    s += __shfl_xor(s, 8, 64);
    s += __shfl_xor(s, 4, 64);
    s += __shfl_xor(s, 2, 64);
    s += __shfl_xor(s, 1, 64);
    return s;
}
__device__ __forceinline__ float bcast_lane(float x, int lane) {
    return __uint_as_float((unsigned)__builtin_amdgcn_readlane((int)__float_as_uint(x), lane));
}

__global__ void zero_acc_kernel(float* acc, float* colsum) {
    int t = blockIdx.x * 256 + threadIdx.x;   // grid 128*256 = 32768
    if (t < 512) acc[t] = 0.f;
    colsum[t] = 0.f;
}

__global__ __launch_bounds__(256) void argmax_pa_kernel(
    const float* __restrict__ la, const float* __restrict__ lb,
    const float* __restrict__ pa, int* __restrict__ argA, int* __restrict__ argB,
    float* __restrict__ acc) {
    int i = blockIdx.x * 256 + threadIdx.x;
    float4 a = *(const float4*)&la[(size_t)i * 4];
    float av[4] = {a.x, a.y, a.z, a.w};
    int ba = 0; float bv = av[0];
#pragma unroll
    for (int c = 1; c < 4; ++c) if (av[c] > bv) { bv = av[c]; ba = c; }
    argA[i] = ba;
    float4 b = *(const float4*)&lb[(size_t)i * 4];
    float bw[4] = {b.x, b.y, b.z, b.w};
    int bbi = 0; float bm = bw[0];
#pragma unroll
    for (int c = 1; c < 4; ++c) if (bw[c] > bm) { bm = bw[c]; bbi = c; }
    argB[i] = bbi;
    float p = pa[i];
#pragma unroll
    for (int off = 32; off > 0; off >>= 1) p += __shfl_down(p, off, 64);
    if ((threadIdx.x & 63) == 0) atomicAdd(&acc[ACC_PA], p);
}

// f32 -> bf16 bulk cast; grid 2048x256, 4 float4-groups/thread
__global__ __launch_bounds__(256) void cast_bf_kernel(
    const float* __restrict__ src, unsigned short* __restrict__ dst) {
    int tid = blockIdx.x * 256 + threadIdx.x;      // < 524288
#pragma unroll
    for (int k = 0; k < 4; ++k) {
        int i4 = tid + k * 524288;                 // < 2097152
        float4 v = *(const float4*)&src[(size_t)i4 * 4];
        ushort4 o;
        o.x = f2bf(v.x); o.y = f2bf(v.y); o.z = f2bf(v.z); o.w = f2bf(v.w);
        *(ushort4*)&dst[(size_t)i4 * 4] = o;
    }
}

// W[256][256] f32 -> Wt[n][k] bf16 (transposed)
__global__ __launch_bounds__(256) void cast_wt_kernel(
    const float* __restrict__ W, unsigned short* __restrict__ Wt) {
    __shared__ float tile[16][17];
    int tx = threadIdx.x & 15, ty = threadIdx.x >> 4;
    int bx = blockIdx.x, by = blockIdx.y;
    tile[ty][tx] = W[(size_t)(by * 16 + ty) * 256 + bx * 16 + tx];
    __syncthreads();
    Wt[(size_t)(bx * 16 + ty) * 256 + by * 16 + tx] = f2bf(tile[tx][ty]);
}

// Y(bf16) = X(bf16, 65536x256) @ W via Wt (bf16, [n][k]).
// Round-8 proven template: 64x64 tile, full-depth global_load_lds staging
// (linear LDS rows + seg XOR swizzle, inverse-swizzled global src),
// ONE barrier, 32 barrier-free MFMAs. Grid (1024 row-tiles, 4 col-tiles):
// row-tile fastest so X-tile re-readers are temporally spread (L3 absorbs).
__global__ __launch_bounds__(256) void gemm_bf_kernel(
    const unsigned short* __restrict__ X, const unsigned short* __restrict__ Wt,
    unsigned short* __restrict__ Y) {
    __shared__ unsigned short As[64 * 256];   // 32 KB
    __shared__ unsigned short Bs[64 * 256];   // 32 KB
    const int t = threadIdx.x;
    const int L = t & 63, wv = t >> 6;
    const int q = L >> 4, n = L & 15;
    const size_t row0 = (size_t)blockIdx.x * 64;
    const int n0 = blockIdx.y * 64;
    {
        const int lrow = L >> 5;
        const int segp = L & 31;
#pragma unroll
        for (int j = 0; j < 8; ++j) {
            int row = wv * 16 + 2 * j + lrow;
            int sseg = segp ^ (row & 7);
            const unsigned short* ga = &X[(row0 + row) * 256 + sseg * 8];
            const unsigned short* gb = &Wt[(size_t)(n0 + row) * 256 + sseg * 8];
            __builtin_amdgcn_global_load_lds((as1cv)ga, (as3v)&As[(wv * 16 + 2 * j) * 256],
                                             16, 0, 0);
            __builtin_amdgcn_global_load_lds((as1cv)gb, (as3v)&Bs[(wv * 16 + 2 * j) * 256],
                                             16, 0, 0);
        }
    }
    f32x4 dot[4];
#pragma unroll
    for (int nt = 0; nt < 4; ++nt) dot[nt] = (f32x4){0.f, 0.f, 0.f, 0.f};
    __syncthreads();

    const int rowa = wv * 16 + n;
    const int sw = n & 7;
#pragma unroll
    for (int c = 0; c < 8; ++c) {
        bf16x8 av = *(const bf16x8*)&As[rowa * 256 + (((c * 4 + q) ^ sw) * 8)];
#pragma unroll
        for (int nt = 0; nt < 4; ++nt) {
            bf16x8 bv = *(const bf16x8*)&Bs[(nt * 16 + n) * 256 + (((c * 4 + q) ^ sw) * 8)];
            dot[nt] = __builtin_amdgcn_mfma_f32_16x16x32_bf16(av, bv, dot[nt], 0, 0, 0);
        }
    }
#pragma unroll
    for (int nt = 0; nt < 4; ++nt)
#pragma unroll
        for (int r = 0; r < 4; ++r) {
            size_t row = row0 + wv * 16 + q * 4 + r;
            Y[row * 256 + n0 + nt * 16 + n] = f2bf(dot[nt][r]);
        }
}

// y_bf16_out = LN(leaky_relu(y_bf16_in + bias)) * g + be ; optional row sq-norms
__global__ __launch_bounds__(256) void ln_bf_kernel(
    const unsigned short* __restrict__ Yin, unsigned short* __restrict__ Yout,
    const float* __restrict__ bias, const float* __restrict__ gam,
    const float* __restrict__ bet, float* __restrict__ norms) {
    int lane = threadIdx.x & 63;
    int wv = threadIdx.x >> 6;
    size_t row = (size_t)blockIdx.x * 4 + wv;
    ushort4 y4 = *(const ushort4*)&Yin[row * 256 + lane * 4];
    float4 b4 = *(const float4*)&bias[lane * 4];
    float h[4] = {bf2f(y4.x) + b4.x, bf2f(y4.y) + b4.y, bf2f(y4.z) + b4.z, bf2f(y4.w) + b4.w};
#pragma unroll
    for (int e = 0; e < 4; ++e) h[e] = h[e] >= 0.f ? h[e] : 0.01f * h[e];
    float s = h[0] + h[1] + h[2] + h[3];
    float sq = h[0] * h[0] + h[1] * h[1] + h[2] * h[2] + h[3] * h[3];
#pragma unroll
    for (int off = 32; off > 0; off >>= 1) {
        s += __shfl_down(s, off, 64);
        sq += __shfl_down(sq, off, 64);
    }
    s = __shfl(s, 0, 64); sq = __shfl(sq, 0, 64);
    float mean = s * (1.f / 256.f);
    float var = fmaxf(sq * (1.f / 256.f) - mean * mean, 0.f);
    float inv = rsqrtf(var + 1e-5f);
    float4 g4 = *(const float4*)&gam[lane * 4];
    float4 e4 = *(const float4*)&bet[lane * 4];
    float gv[4] = {g4.x, g4.y, g4.z, g4.w};
    float ev[4] = {e4.x, e4.y, e4.z, e4.w};
    ushort4 o4; float nr = 0.f;
    {
        unsigned short ob[4];
#pragma unroll
        for (int e = 0; e < 4; ++e) {
            float o = (h[e] - mean) * inv * gv[e] + ev[e];
            ob[e] = f2bf(o);
            float orr = bf2f(ob[e]);
            nr += orr * orr;
        }
        o4.x = ob[0]; o4.y = ob[1]; o4.z = ob[2]; o4.w = ob[3];
    }
    *(ushort4*)&Yout[row * 256 + lane * 4] = o4;
    if (norms) {
#pragma unroll
        for (int off = 32; off > 0; off >>= 1) nr += __shfl_down(nr, off, 64);
        if (lane == 0) norms[row] = nr;
    }
}

// cdist via MFMA + in/out loss partial + K(bf16) = exp(-2*cost) + K column sums.
// Full-tile staging via global_load_lds; one staging barrier; 32 MFMAs barrier-free.
__global__ __launch_bounds__(256) void cost_mfma_kernel(
    const unsigned short* __restrict__ E, const float* __restrict__ norms,
    const int* __restrict__ argA, const int* __restrict__ argB,
    const float* __restrict__ pa, const float* __restrict__ pb,
    unsigned short* __restrict__ Kb16, float* __restrict__ acc,
    float* __restrict__ colsum) {
    __shared__ unsigned short As[64 * 256];   // 32 KB, row stride 512B, seg-swizzled
    __shared__ unsigned short Bs[64 * 256];   // 32 KB  (total exactly 64 KB)
    const int t = threadIdx.x;
    const int L = t & 63, wv = t >> 6;
    const int q = L >> 4, n = L & 15;
    const int b = blockIdx.z;
    const int i0 = blockIdx.y * 64, j0 = blockIdx.x * 64;
    const unsigned short* eA = E + (size_t)b * 512 * 256;
    const unsigned short* eB = E + (size_t)(32768 + b * 512) * 256;

    {
        const int lrow = L >> 5;
        const int segp = L & 31;
#pragma unroll
        for (int j = 0; j < 8; ++j) {
            int row = wv * 16 + 2 * j + lrow;
            int sseg = segp ^ (row & 7);
            const unsigned short* ga = &eA[(size_t)(i0 + row) * 256 + sseg * 8];
            const unsigned short* gb = &eB[(size_t)(j0 + row) * 256 + sseg * 8];
            __builtin_amdgcn_global_load_lds((as1cv)ga, (as3v)&As[(wv * 16 + 2 * j) * 256],
                                             16, 0, 0);
            __builtin_amdgcn_global_load_lds((as1cv)gb, (as3v)&Bs[(wv * 16 + 2 * j) * 256],
                                             16, 0, 0);
        }
    }
    f32x4 dot[4];
#pragma unroll
    for (int nt = 0; nt < 4; ++nt) dot[nt] = (f32x4){0.f, 0.f, 0.f, 0.f};
    __syncthreads();   // single staging drain

    const int rowa = wv * 16 + n;
    const int sw = n & 7;
#pragma unroll
    for (int c = 0; c < 8; ++c) {
        bf16x8 av = *(const bf16x8*)&As[rowa * 256 + (((c * 4 + q) ^ sw) * 8)];
#pragma unroll
        for (int nt = 0; nt < 4; ++nt) {
            int rowb = nt * 16 + n;
            bf16x8 bv = *(const bf16x8*)&Bs[rowb * 256 + (((c * 4 + q) ^ sw) * 8)];
            dot[nt] = __builtin_amdgcn_mfma_f32_16x16x32_bf16(av, bv, dot[nt], 0, 0, 0);
        }
    }

    int base_row = i0 + wv * 16 + q * 4;
    float nA[4], pAr[4]; int cA[4];
#pragma unroll
    for (int rr = 0; rr < 4; ++rr) {
        nA[rr] = norms[b * 512 + base_row + rr];
        pAr[rr] = pa[b * 512 + base_row + rr];
        cA[rr] = argA[b * 512 + base_row + rr];
    }
    float part = 0.f;
    float csnt[4];
#pragma unroll
    for (int nt = 0; nt < 4; ++nt) {
        int col = j0 + nt * 16 + n;
        float nB = norms[32768 + b * 512 + col];
        float pB = pb[b * 512 + col];
        int cB = argB[b * 512 + col];
        float cloc = 0.f;
#pragma unroll
        for (int rr = 0; rr < 4; ++rr) {
            float d2 = nA[rr] + nB - 2.f * dot[nt][rr];
            float c = sqrtf(fmaxf(d2, 0.f));
            float pm = pAr[rr] * pB;
            float cc = c + (BIGF - BIGF * pm);
            float sgn = (cA[rr] == cB) ? 1.f : -1.f;
            part += cc * sgn * pm;
            unsigned short kb = f2bf(expf(-2.f * cc));
            Kb16[((size_t)b * 512 + base_row + rr) * 512 + col] = kb;
            cloc += bf2f(kb);
        }
        csnt[nt] = cloc;
    }
    // reductions: reuse As space (all tile reads complete after barrier)
    __syncthreads();
    float* red = (float*)As;   // [0..255]: per-wave col partials; [256..259]: loss partials
#pragma unroll
    for (int nt = 0; nt < 4; ++nt) {
        float sq2 = csnt[nt];
        sq2 += __shfl_xor(sq2, 16, 64);
        sq2 += __shfl_xor(sq2, 32, 64);
        if (L < 16) red[wv * 64 + nt * 16 + L] = sq2;
    }
    {
        float pw = part;
#pragma unroll
        for (int off = 32; off > 0; off >>= 1) pw += __shfl_down(pw, off, 64);
        if (L == 0) red[256 + wv] = pw;
    }
    __syncthreads();
    if (t < 64)
        atomicAdd(&colsum[(size_t)b * 512 + j0 + t],
                  red[t] + red[64 + t] + red[128 + t] + red[192 + t]);
    if (t == 0)
        atomicAdd(&acc[ACC_IN + b], red[256] + red[257] + red[258] + red[259]);
}

// Fused Sinkhorn: 9 fused passes only (pass-0 folded into cost via colsum;
// final u-pass folded into sup via u_i*512 = 1/rowsum). Writes v only.
__global__ __launch_bounds__(1024) void sinkhorn_kernel(
    const unsigned short* __restrict__ Kb16, const float* __restrict__ colsum,
    float* __restrict__ v) {
    const int b = blockIdx.x;
    const unsigned short* Kb = Kb16 + (size_t)b * 262144;
    __shared__ float vv[512];
    __shared__ float cp[16][512];
    const int t = threadIdx.x, wv = t >> 6, l = t & 63;
    const unsigned short* base = Kb + (size_t)(wv * 32) * 512 + l * 8;

    // v1_j = (1/512) / (colsum_j/512) = 1/colsum_j
    if (t < 512) vv[t] = 1.f / colsum[(size_t)b * 512 + t];
    __syncthreads();

    for (int it = 1; it <= 9; ++it) {
        float vr[8];
        *(f32x4*)&vr[0] = *(const f32x4*)&vv[l * 8];
        *(f32x4*)&vr[4] = *(const f32x4*)&vv[l * 8 + 4];
        float cs[8];
#pragma unroll
        for (int e = 0; e < 8; ++e) cs[e] = 0.f;
#pragma unroll 2
        for (int g = 0; g < 8; ++g) {
            const unsigned short* gb = base + (size_t)(g * 4) * 512;
            uint4 w0 = *(const uint4*)(gb);
            uint4 w1 = *(const uint4*)(gb + 512);
            uint4 w2 = *(const uint4*)(gb + 1024);
            uint4 w3 = *(const uint4*)(gb + 1536);
            float k0[8], k1[8], k2[8], k3[8];
            unpack8(w0, k0); unpack8(w1, k1); unpack8(w2, k2); unpack8(w3, k3);
            float p0 = dot8(k0, vr);
            float p1 = dot8(k1, vr);
            float p2 = dot8(k2, vr);
            float p3 = dot8(k3, vr);
            float s = packed_reduce4(p0, p1, p2, p3, l);
            float us = 0.001953125f * __builtin_amdgcn_rcpf(s);
            float uA = bcast_lane(us, 0);
            float uC = bcast_lane(us, 16);
            float uB = bcast_lane(us, 32);
            float uD = bcast_lane(us, 48);
#pragma unroll
            for (int e = 0; e < 8; ++e) {
                float c = fmaf(k0[e], uA, cs[e]);
                c = fmaf(k1[e], uB, c);
                c = fmaf(k2[e], uC, c);
                cs[e] = fmaf(k3[e], uD, c);
            }
        }
        *(f32x4*)&cp[wv][l * 8]     = *(f32x4*)&cs[0];
        *(f32x4*)&cp[wv][l * 8 + 4] = *(f32x4*)&cs[4];
        __syncthreads();
        if (t < 512) {
            float ss = 0.f;
#pragma unroll
            for (int k = 0; k < 16; ++k) ss += cp[k][t];
            vv[t] = (1.f / 512.f) / ss;
        }
        __syncthreads();
    }
    if (t < 512) v[(size_t)b * 512 + t] = vv[t];
}

// sup loss; computes u_i on the fly: u_i*512 = 1/(K@v)_i (exact binade-equiv
// to the old separate u-pass). One block per 8 rows: row = half-wave (32 lanes),
// each lane owns 16 consecutive cols.
__global__ __launch_bounds__(256) void sup_kernel(
    const unsigned short* __restrict__ Kb16, const float* __restrict__ v,
    const float* __restrict__ rel, const float* __restrict__ pa,
    float* __restrict__ acc) {
    const int b = blockIdx.x >> 6;
    const int rg = blockIdx.x & 63;
    const int t = threadIdx.x;
    const int h = t >> 5;               // row within group: 0..7
    const int c = t & 31;               // col chunk: cols c*16..+15
    const int row = rg * 8 + h;
    const unsigned int* kp =
        (const unsigned int*)(Kb16 + ((size_t)b * 512 + row) * 512 + c * 16);
    uint4 kw0 = *(const uint4*)(kp);
    uint4 kw1 = *(const uint4*)(kp + 4);
    float k[16];
    unpack8(kw0, k); unpack8(kw1, k + 8);
    float vr[16];
    *(f32x4*)&vr[0]  = *(const f32x4*)&v[b * 512 + c * 16];
    *(f32x4*)&vr[4]  = *(const f32x4*)&v[b * 512 + c * 16 + 4];
    *(f32x4*)&vr[8]  = *(const f32x4*)&v[b * 512 + c * 16 + 8];
    *(f32x4*)&vr[12] = *(const f32x4*)&v[b * 512 + c * 16 + 12];
    float rs = 0.f;
#pragma unroll
    for (int e = 0; e < 16; ++e) rs = fmaf(k[e], vr[e], rs);
#pragma unroll
    for (int off = 16; off > 0; off >>= 1) rs += __shfl_xor(rs, off, 32);
    float inv = 1.f / rs;               // = u_i * 512 (exact divide)
    float part = 0.f;
    const float* rp = &rel[((size_t)b * 512 + row) * 512 + c * 16];
#pragma unroll
    for (int e = 0; e < 16; e += 4) {
        float4 r4 = *(const float4*)(rp + e);
        float d0 = k[e]     * vr[e]     * inv - r4.x;
        float d1 = k[e + 1] * vr[e + 1] * inv - r4.y;
        float d2 = k[e + 2] * vr[e + 2] * inv - r4.z;
        float d3 = k[e + 3] * vr[e + 3] * inv - r4.w;
        part += d0 * d0 + d1 * d1 + d2 * d2 + d3 * d3;
    }
    part *= pa[b * 512 + row];
    float tot = block_reduce_256(part);
    if (t == 0) atomicAdd(&acc[ACC_SUP + (blockIdx.x & 255)], tot);
}

__global__ __launch_bounds__(256) void final_kernel(const float* __restrict__ acc,
                                                    float* __restrict__ out) {
    int t = threadIdx.x;
    float vin = (t < 64) ? acc[ACC_IN + t] : 0.f;
    float sIn = block_reduce_256(vin);
    float vsup = acc[ACC_SUP + t];
    float sSup = block_reduce_256(vsup);
    if (t == 0)
        out[0] = sIn * (1.f / 16777216.f) + 10.f * sSup / acc[ACC_PA];
}

extern "C" void kernel_launch(void* const* d_in, const int* in_sizes, int n_in,
                              void* d_out, int out_size, void* d_ws, size_t ws_size,
                              hipStream_t stream) {
    const float* la  = (const float*)d_in[0];
    const float* lb  = (const float*)d_in[1];
    const float* xA  = (const float*)d_in[2];
    const float* xB  = (const float*)d_in[3];
    const float* rel = (const float*)d_in[4];
    const float* pa  = (const float*)d_in[5];
    const float* pb  = (const float*)d_in[6];
    const float* W1  = (const float*)d_in[7];
    const float* b1  = (const float*)d_in[8];
    const float* g1  = (const float*)d_in[9];
    const float* be1 = (const float*)d_in[10];
    const float* W2  = (const float*)d_in[11];
    const float* b2  = (const float*)d_in[12];
    const float* g2  = (const float*)d_in[13];
    const float* be2 = (const float*)d_in[14];
    float* out = (float*)d_out;

    float* ws = (float*)d_ws;
    unsigned short* Kb16 = (unsigned short*)(ws + KB_OFF);   // Ybf1/Ybf2 then K
    unsigned short* Xbf  = (unsigned short*)(ws + X_OFF);    // Xbf then Ebf
    unsigned short* Hbf  = (unsigned short*)(ws + H_OFF);
    float* norms = ws + NORM_OFF;
    float* u     = ws + U_OFF;    // colsum staging
    float* v     = ws + V_OFF;
    int* argA    = (int*)(ws + ARGA_OFF);
    int* argB    = (int*)(ws + ARGB_OFF);
    float* acc   = ws + ACC_OFF;
    unsigned short* Wt1 = (unsigned short*)(ws + WT1_OFF);
    unsigned short* Wt2 = (unsigned short*)(ws + WT2_OFF);

    zero_acc_kernel<<<128, 256, 0, stream>>>(acc, u);        // zero acc + colsum
    argmax_pa_kernel<<<128, 256, 0, stream>>>(la, lb, pa, argA, argB, acc);

    // casts
    cast_bf_kernel<<<2048, 256, 0, stream>>>(xA, Xbf);
    cast_bf_kernel<<<2048, 256, 0, stream>>>(xB, Xbf + (size_t)MROWS * DIM);
    cast_wt_kernel<<<dim3(16, 16), 256, 0, stream>>>(W1, Wt1);
    cast_wt_kernel<<<dim3(16, 16), 256, 0, stream>>>(W2, Wt2);

    // layer 1
    gemm_bf_kernel<<<dim3(1024, 4), 256, 0, stream>>>(Xbf, Wt1, Kb16);
    ln_bf_kernel<<<16384, 256, 0, stream>>>(Kb16, Hbf, b1, g1, be1, nullptr);
    // layer 2
    gemm_bf_kernel<<<dim3(1024, 4), 256, 0, stream>>>(Hbf, Wt2, Kb16);
    ln_bf_kernel<<<16384, 256, 0, stream>>>(Kb16, Xbf, b2, g2, be2, norms);  // Ebf -> Xbf buf

    // cost + K (bf16) + column sums
    cost_mfma_kernel<<<dim3(8, 8, 64), 256, 0, stream>>>(Xbf, norms, argA, argB, pa, pb,
                                                         Kb16, acc, u);

    // sinkhorn: 9 fused K-passes (pass-0 in cost, final u-pass in sup)
    sinkhorn_kernel<<<64, 1024, 0, stream>>>(Kb16, u, v);

    sup_kernel<<<4096, 256, 0, stream>>>(Kb16, v, rel, pa, acc);
    final_kernel<<<1, 256, 0, stream>>>(acc, out);
}

// Round 10
// 386.774 us; speedup vs baseline: 1.0865x; 1.0345x over previous
//
#include <hip/hip_runtime.h>
#include <math.h>

// Problem constants
#define BSZ 64
#define NPTS 512
#define DIM 256
#define MROWS 32768      // BSZ*NPTS
#define TOTROWS 65536
#define BIGF 1.0e9f

typedef __bf16 bf16x8 __attribute__((ext_vector_type(8)));
typedef float  f32x4  __attribute__((ext_vector_type(4)));
typedef __attribute__((address_space(1))) const void* as1cv;
typedef __attribute__((address_space(3))) void* as3v;

// ws layout (float offsets)
#define KB_OFF    0ull          // 8388608 floats as ushort[16777216]: Ybf1 -> Ybf2 -> K(bf16)
#define X_OFF     8388608ull    // 8388608 floats as ushort[16777216]: Xbf -> Ebf
#define H_OFF     16777216ull   // 8388608 floats as ushort[16777216]: Hbf
#define NORM_OFF  25165824ull   // 65536 f32
#define U_OFF     25231360ull   // 32768 f32 (colsum staged here pre-sinkhorn)
#define V_OFF     25264128ull   // 32768 f32
#define ARGA_OFF  25296896ull   // 32768 int
#define ARGB_OFF  25329664ull   // 32768 int
#define ACC_OFF   25362432ull   // 512 f32
#define WT1_OFF   25362944ull   // 32768 floats as ushort[65536]
#define WT2_OFF   25395712ull   // 32768 floats as ushort[65536]

#define ACC_PA   0
#define ACC_IN   1     // 64 slots
#define ACC_SUP  65    // 256 slots
#define ACC_CNT  321

__device__ __forceinline__ float bf2f(unsigned short h) {
    return __uint_as_float(((unsigned int)h) << 16);
}
__device__ __forceinline__ unsigned short f2bf(float f) {
    unsigned int u = __float_as_uint(f);
    u = (u + 0x7FFFu + ((u >> 16) & 1u)) >> 16;
    return (unsigned short)u;
}

// re-entrant, 256-thread blocks only
__device__ __forceinline__ float block_reduce_256(float val) {
    __shared__ float sh[4];
    int lane = threadIdx.x & 63;
    int wv = threadIdx.x >> 6;
    __syncthreads();
#pragma unroll
    for (int off = 32; off > 0; off >>= 1) val += __shfl_down(val, off, 64);
    if (lane == 0) sh[wv] = val;
    __syncthreads();
    float r = 0.f;
    if (wv == 0 && lane < 4) r = sh[lane];
    if (wv == 0) {
        r += __shfl_down(r, 2, 64);
        r += __shfl_down(r, 1, 64);
    }
    return r;  // valid in thread 0
}

__device__ __forceinline__ void unpack8(uint4 w, float* k) {
    k[0] = __uint_as_float(w.x << 16);
    k[1] = __uint_as_float(w.x & 0xFFFF0000u);
    k[2] = __uint_as_float(w.y << 16);
    k[3] = __uint_as_float(w.y & 0xFFFF0000u);
    k[4] = __uint_as_float(w.z << 16);
    k[5] = __uint_as_float(w.z & 0xFFFF0000u);
    k[6] = __uint_as_float(w.w << 16);
    k[7] = __uint_as_float(w.w & 0xFFFF0000u);
}
__device__ __forceinline__ float dot8(const float* k, const float* vr) {
    float rs = k[0] * vr[0];
    rs = fmaf(k[1], vr[1], rs); rs = fmaf(k[2], vr[2], rs);
    rs = fmaf(k[3], vr[3], rs); rs = fmaf(k[4], vr[4], rs);
    rs = fmaf(k[5], vr[5], rs); rs = fmaf(k[6], vr[6], rs);
    return fmaf(k[7], vr[7], rs);
}

// Packed 4-row all-lanes reduce: rows A,B,C,D per-lane partials -> row sums,
// replicated within 16-lane groups: g0=A, g1=C, g2=B, g3=D. 10 DS ops for 4 rows.
__device__ __forceinline__ float packed_reduce4(float p0, float p1, float p2, float p3, int l) {
    p0 += __shfl_xor(p0, 32, 64);
    p1 += __shfl_xor(p1, 32, 64);
    p2 += __shfl_xor(p2, 32, 64);
    p3 += __shfl_xor(p3, 32, 64);
    float m1 = (l & 32) ? p1 : p0;
    float m2 = (l & 32) ? p3 : p2;
    m1 += __shfl_xor(m1, 16, 64);
    m2 += __shfl_xor(m2, 16, 64);
    float s = (l & 16) ? m2 : m1;
    s += __shfl_xor(s, 8, 64);
    s += __shfl_xor(s, 4, 64);
    s += __shfl_xor(s, 2, 64);
    s += __shfl_xor(s, 1, 64);
    return s;
}
__device__ __forceinline__ float bcast_lane(float x, int lane) {
    return __uint_as_float((unsigned)__builtin_amdgcn_readlane((int)__float_as_uint(x), lane));
}

__global__ void zero_acc_kernel(float* acc, float* colsum) {
    int t = blockIdx.x * 256 + threadIdx.x;   // grid 128*256 = 32768
    if (t < 512) acc[t] = 0.f;
    colsum[t] = 0.f;
}

__global__ __launch_bounds__(256) void argmax_pa_kernel(
    const float* __restrict__ la, const float* __restrict__ lb,
    const float* __restrict__ pa, int* __restrict__ argA, int* __restrict__ argB,
    float* __restrict__ acc) {
    int i = blockIdx.x * 256 + threadIdx.x;
    float4 a = *(const float4*)&la[(size_t)i * 4];
    float av[4] = {a.x, a.y, a.z, a.w};
    int ba = 0; float bv = av[0];
#pragma unroll
    for (int c = 1; c < 4; ++c) if (av[c] > bv) { bv = av[c]; ba = c; }
    argA[i] = ba;
    float4 b = *(const float4*)&lb[(size_t)i * 4];
    float bw[4] = {b.x, b.y, b.z, b.w};
    int bbi = 0; float bm = bw[0];
#pragma unroll
    for (int c = 1; c < 4; ++c) if (bw[c] > bm) { bm = bw[c]; bbi = c; }
    argB[i] = bbi;
    float p = pa[i];
#pragma unroll
    for (int off = 32; off > 0; off >>= 1) p += __shfl_down(p, off, 64);
    if ((threadIdx.x & 63) == 0) atomicAdd(&acc[ACC_PA], p);
}

// f32 -> bf16 bulk cast; grid 2048x256, 4 float4-groups/thread
__global__ __launch_bounds__(256) void cast_bf_kernel(
    const float* __restrict__ src, unsigned short* __restrict__ dst) {
    int tid = blockIdx.x * 256 + threadIdx.x;      // < 524288
#pragma unroll
    for (int k = 0; k < 4; ++k) {
        int i4 = tid + k * 524288;                 // < 2097152
        float4 v = *(const float4*)&src[(size_t)i4 * 4];
        ushort4 o;
        o.x = f2bf(v.x); o.y = f2bf(v.y); o.z = f2bf(v.z); o.w = f2bf(v.w);
        *(ushort4*)&dst[(size_t)i4 * 4] = o;
    }
}

// W[256][256] f32 -> Wt[n][k] bf16 (transposed)
__global__ __launch_bounds__(256) void cast_wt_kernel(
    const float* __restrict__ W, unsigned short* __restrict__ Wt) {
    __shared__ float tile[16][17];
    int tx = threadIdx.x & 15, ty = threadIdx.x >> 4;
    int bx = blockIdx.x, by = blockIdx.y;
    tile[ty][tx] = W[(size_t)(by * 16 + ty) * 256 + bx * 16 + tx];
    __syncthreads();
    Wt[(size_t)(bx * 16 + ty) * 256 + by * 16 + tx] = f2bf(tile[tx][ty]);
}

// Y(bf16) = X(bf16, 65536x256) @ W via Wt (bf16, [n][k]).
// 64x64 tile, full-depth global_load_lds staging, ONE barrier, 32 MFMAs.
__global__ __launch_bounds__(256) void gemm_bf_kernel(
    const unsigned short* __restrict__ X, const unsigned short* __restrict__ Wt,
    unsigned short* __restrict__ Y) {
    __shared__ unsigned short As[64 * 256];   // 32 KB
    __shared__ unsigned short Bs[64 * 256];   // 32 KB
    const int t = threadIdx.x;
    const int L = t & 63, wv = t >> 6;
    const int q = L >> 4, n = L & 15;
    const size_t row0 = (size_t)blockIdx.x * 64;
    const int n0 = blockIdx.y * 64;
    {
        const int lrow = L >> 5;
        const int segp = L & 31;
#pragma unroll
        for (int j = 0; j < 8; ++j) {
            int row = wv * 16 + 2 * j + lrow;
            int sseg = segp ^ (row & 7);
            const unsigned short* ga = &X[(row0 + row) * 256 + sseg * 8];
            const unsigned short* gb = &Wt[(size_t)(n0 + row) * 256 + sseg * 8];
            __builtin_amdgcn_global_load_lds((as1cv)ga, (as3v)&As[(wv * 16 + 2 * j) * 256],
                                             16, 0, 0);
            __builtin_amdgcn_global_load_lds((as1cv)gb, (as3v)&Bs[(wv * 16 + 2 * j) * 256],
                                             16, 0, 0);
        }
    }
    f32x4 dot[4];
#pragma unroll
    for (int nt = 0; nt < 4; ++nt) dot[nt] = (f32x4){0.f, 0.f, 0.f, 0.f};
    __syncthreads();

    const int rowa = wv * 16 + n;
    const int sw = n & 7;
#pragma unroll
    for (int c = 0; c < 8; ++c) {
        bf16x8 av = *(const bf16x8*)&As[rowa * 256 + (((c * 4 + q) ^ sw) * 8)];
#pragma unroll
        for (int nt = 0; nt < 4; ++nt) {
            bf16x8 bv = *(const bf16x8*)&Bs[(nt * 16 + n) * 256 + (((c * 4 + q) ^ sw) * 8)];
            dot[nt] = __builtin_amdgcn_mfma_f32_16x16x32_bf16(av, bv, dot[nt], 0, 0, 0);
        }
    }
#pragma unroll
    for (int nt = 0; nt < 4; ++nt)
#pragma unroll
        for (int r = 0; r < 4; ++r) {
            size_t row = row0 + wv * 16 + q * 4 + r;
            Y[row * 256 + n0 + nt * 16 + n] = f2bf(dot[nt][r]);
        }
}

// y_bf16_out = LN(leaky_relu(y_bf16_in + bias)) * g + be ; optional row sq-norms
__global__ __launch_bounds__(256) void ln_bf_kernel(
    const unsigned short* __restrict__ Yin, unsigned short* __restrict__ Yout,
    const float* __restrict__ bias, const float* __restrict__ gam,
    const float* __restrict__ bet, float* __restrict__ norms) {
    int lane = threadIdx.x & 63;
    int wv = threadIdx.x >> 6;
    size_t row = (size_t)blockIdx.x * 4 + wv;
    ushort4 y4 = *(const ushort4*)&Yin[row * 256 + lane * 4];
    float4 b4 = *(const float4*)&bias[lane * 4];
    float h[4] = {bf2f(y4.x) + b4.x, bf2f(y4.y) + b4.y, bf2f(y4.z) + b4.z, bf2f(y4.w) + b4.w};
#pragma unroll
    for (int e = 0; e < 4; ++e) h[e] = h[e] >= 0.f ? h[e] : 0.01f * h[e];
    float s = h[0] + h[1] + h[2] + h[3];
    float sq = h[0] * h[0] + h[1] * h[1] + h[2] * h[2] + h[3] * h[3];
#pragma unroll
    for (int off = 32; off > 0; off >>= 1) {
        s += __shfl_down(s, off, 64);
        sq += __shfl_down(sq, off, 64);
    }
    s = __shfl(s, 0, 64); sq = __shfl(sq, 0, 64);
    float mean = s * (1.f / 256.f);
    float var = fmaxf(sq * (1.f / 256.f) - mean * mean, 0.f);
    float inv = rsqrtf(var + 1e-5f);
    float4 g4 = *(const float4*)&gam[lane * 4];
    float4 e4 = *(const float4*)&bet[lane * 4];
    float gv[4] = {g4.x, g4.y, g4.z, g4.w};
    float ev[4] = {e4.x, e4.y, e4.z, e4.w};
    ushort4 o4; float nr = 0.f;
    {
        unsigned short ob[4];
#pragma unroll
        for (int e = 0; e < 4; ++e) {
            float o = (h[e] - mean) * inv * gv[e] + ev[e];
            ob[e] = f2bf(o);
            float orr = bf2f(ob[e]);
            nr += orr * orr;
        }
        o4.x = ob[0]; o4.y = ob[1]; o4.z = ob[2]; o4.w = ob[3];
    }
    *(ushort4*)&Yout[row * 256 + lane * 4] = o4;
    if (norms) {
#pragma unroll
        for (int off = 32; off > 0; off >>= 1) nr += __shfl_down(nr, off, 64);
        if (lane == 0) norms[row] = nr;
    }
}

// Panel cost kernel: block = (batch b, 64-row panel i0). 512 threads (8 waves).
// Stage A once; loop over 8 B column-tiles, double-buffered global_load_lds:
// {issue next-B stage -> 16 MFMA (A fragments in regs) -> epilogue -> barrier}.
// Wave wv: rows rh*16 (rh=wv&3), col-half ch=wv>>2 (nt = ch*2+nt').
// colsum partials in per-wave LDS slots; in-loss in registers across tiles.
__global__ __launch_bounds__(512) void cost_mfma_kernel(
    const unsigned short* __restrict__ E, const float* __restrict__ norms,
    const int* __restrict__ argA, const int* __restrict__ argB,
    const float* __restrict__ pa, const float* __restrict__ pb,
    unsigned short* __restrict__ Kb16, float* __restrict__ acc,
    float* __restrict__ colsum) {
    __shared__ unsigned short As[64 * 256];       // 32 KB
    __shared__ unsigned short Bs[2][64 * 256];    // 64 KB
    __shared__ float cswave[8][256];              // 8 KB per-wave colsum partials
    __shared__ float redp[8];
    const int t = threadIdx.x;
    const int L = t & 63, wv = t >> 6;
    const int q = L >> 4, n = L & 15;
    const int rh = wv & 3, ch = wv >> 2;
    // b = id&63 so a batch's 8 panels share an XCD (id%8 == b%8)
    const int b = blockIdx.x & 63;
    const int i0 = (blockIdx.x >> 6) * 64;
    const unsigned short* eA = E + (size_t)b * 512 * 256;
    const unsigned short* eB = E + (size_t)(32768 + b * 512) * 256;
    const int lrow = L >> 5, segp = L & 31;

    // prologue: stage A panel + B tile 0 (wave wv stages rows wv*8..+7)
#pragma unroll
    for (int jj = 0; jj < 4; ++jj) {
        int row = wv * 8 + 2 * jj + lrow;
        int sseg = segp ^ (row & 7);
        __builtin_amdgcn_global_load_lds((as1cv)&eA[(size_t)(i0 + row) * 256 + sseg * 8],
                                         (as3v)&As[(wv * 8 + 2 * jj) * 256], 16, 0, 0);
        __builtin_amdgcn_global_load_lds((as1cv)&eB[(size_t)row * 256 + sseg * 8],
                                         (as3v)&Bs[0][(wv * 8 + 2 * jj) * 256], 16, 0, 0);
    }
    // row-side constants (independent of column tile)
    const int base_row = i0 + rh * 16 + q * 4;
    float nA[4], pAr[4]; int cA[4];
#pragma unroll
    for (int rr = 0; rr < 4; ++rr) {
        nA[rr] = norms[b * 512 + base_row + rr];
        pAr[rr] = pa[b * 512 + base_row + rr];
        cA[rr] = argA[b * 512 + base_row + rr];
    }
    float part = 0.f;
    __syncthreads();   // A + B0 staged

    // hoist A fragments to registers (rows rh*16+n)
    const int rowa = rh * 16 + n;
    const int sw = n & 7;
    bf16x8 areg[8];
#pragma unroll
    for (int c = 0; c < 8; ++c)
        areg[c] = *(const bf16x8*)&As[rowa * 256 + (((c * 4 + q) ^ sw) * 8)];

    for (int j = 0; j < 8; ++j) {
        const int cur = j & 1;
        if (j < 7) {   // issue next B tile into the buffer freed at last barrier
#pragma unroll
            for (int jj = 0; jj < 4; ++jj) {
                int row = wv * 8 + 2 * jj + lrow;
                int sseg = segp ^ (row & 7);
                __builtin_amdgcn_global_load_lds(
                    (as1cv)&eB[(size_t)((j + 1) * 64 + row) * 256 + sseg * 8],
                    (as3v)&Bs[cur ^ 1][(wv * 8 + 2 * jj) * 256], 16, 0, 0);
            }
        }
        f32x4 dot[2];
        dot[0] = (f32x4){0.f, 0.f, 0.f, 0.f};
        dot[1] = (f32x4){0.f, 0.f, 0.f, 0.f};
#pragma unroll
        for (int c = 0; c < 8; ++c) {
#pragma unroll
            for (int np = 0; np < 2; ++np) {
                int nt = ch * 2 + np;
                bf16x8 bv = *(const bf16x8*)&Bs[cur][(nt * 16 + n) * 256 +
                                                     (((c * 4 + q) ^ sw) * 8)];
                dot[np] = __builtin_amdgcn_mfma_f32_16x16x32_bf16(areg[c], bv, dot[np], 0, 0, 0);
            }
        }
        // epilogue: cols j*64 + nt*16 + n
#pragma unroll
        for (int np = 0; np < 2; ++np) {
            int nt = ch * 2 + np;
            int col = j * 64 + nt * 16 + n;
            float nB = norms[32768 + b * 512 + col];
            float pB = pb[b * 512 + col];
            int cB = argB[b * 512 + col];
            float cloc = 0.f;
#pragma unroll
            for (int rr = 0; rr < 4; ++rr) {
                float d2 = nA[rr] + nB - 2.f * dot[np][rr];
                float c = sqrtf(fmaxf(d2, 0.f));
                float pm = pAr[rr] * pB;
                float cc = c + (BIGF - BIGF * pm);
                float sgn = (cA[rr] == cB) ? 1.f : -1.f;
                part += cc * sgn * pm;
                unsigned short kb = f2bf(expf(-2.f * cc));
                Kb16[((size_t)b * 512 + base_row + rr) * 512 + col] = kb;
                cloc += bf2f(kb);
            }
            // reduce over q (4 lanes per col); lane<16 writes this wave's slot
            cloc += __shfl_xor(cloc, 16, 64);
            cloc += __shfl_xor(cloc, 32, 64);
            if (L < 16) cswave[wv][j * 32 + np * 16 + L] = cloc;
        }
        __syncthreads();   // drains next-B stage + retires all Bs[cur] reads
    }

    // final reductions
    {
        float pw = part;
#pragma unroll
        for (int off = 32; off > 0; off >>= 1) pw += __shfl_down(pw, off, 64);
        if (L == 0) redp[wv] = pw;
    }
    __syncthreads();
    {
        int c = t & 511;
        int local = ((c >> 6) << 5) | (c & 31);
        int cch = (c >> 5) & 1;
        float s = cswave[4 * cch][local] + cswave[4 * cch + 1][local] +
                  cswave[4 * cch + 2][local] + cswave[4 * cch + 3][local];
        atomicAdd(&colsum[(size_t)b * 512 + c], s);
    }
    if (t == 0) {
        float s = 0.f;
#pragma unroll
        for (int k = 0; k < 8; ++k) s += redp[k];
        atomicAdd(&acc[ACC_IN + b], s);
    }
}

// Fused Sinkhorn: 9 fused passes only (pass-0 folded into cost via colsum;
// final u-pass folded into sup via u_i*512 = 1/rowsum). Writes v only.
__global__ __launch_bounds__(1024) void sinkhorn_kernel(
    const unsigned short* __restrict__ Kb16, const float* __restrict__ colsum,
    float* __restrict__ v) {
    const int b = blockIdx.x;
    const unsigned short* Kb = Kb16 + (size_t)b * 262144;
    __shared__ float vv[512];
    __shared__ float cp[16][512];
    const int t = threadIdx.x, wv = t >> 6, l = t & 63;
    const unsigned short* base = Kb + (size_t)(wv * 32) * 512 + l * 8;

    if (t < 512) vv[t] = 1.f / colsum[(size_t)b * 512 + t];
    __syncthreads();

    for (int it = 1; it <= 9; ++it) {
        float vr[8];
        *(f32x4*)&vr[0] = *(const f32x4*)&vv[l * 8];
        *(f32x4*)&vr[4] = *(const f32x4*)&vv[l * 8 + 4];
        float cs[8];
#pragma unroll
        for (int e = 0; e < 8; ++e) cs[e] = 0.f;
#pragma unroll 2
        for (int g = 0; g < 8; ++g) {
            const unsigned short* gb = base + (size_t)(g * 4) * 512;
            uint4 w0 = *(const uint4*)(gb);
            uint4 w1 = *(const uint4*)(gb + 512);
            uint4 w2 = *(const uint4*)(gb + 1024);
            uint4 w3 = *(const uint4*)(gb + 1536);
            float k0[8], k1[8], k2[8], k3[8];
            unpack8(w0, k0); unpack8(w1, k1); unpack8(w2, k2); unpack8(w3, k3);
            float p0 = dot8(k0, vr);
            float p1 = dot8(k1, vr);
            float p2 = dot8(k2, vr);
            float p3 = dot8(k3, vr);
            float s = packed_reduce4(p0, p1, p2, p3, l);
            float us = 0.001953125f * __builtin_amdgcn_rcpf(s);
            float uA = bcast_lane(us, 0);
            float uC = bcast_lane(us, 16);
            float uB = bcast_lane(us, 32);
            float uD = bcast_lane(us, 48);
#pragma unroll
            for (int e = 0; e < 8; ++e) {
                float c = fmaf(k0[e], uA, cs[e]);
                c = fmaf(k1[e], uB, c);
                c = fmaf(k2[e], uC, c);
                cs[e] = fmaf(k3[e], uD, c);
            }
        }
        *(f32x4*)&cp[wv][l * 8]     = *(f32x4*)&cs[0];
        *(f32x4*)&cp[wv][l * 8 + 4] = *(f32x4*)&cs[4];
        __syncthreads();
        if (t < 512) {
            float ss = 0.f;
#pragma unroll
            for (int k = 0; k < 16; ++k) ss += cp[k][t];
            vv[t] = (1.f / 512.f) / ss;
        }
        __syncthreads();
    }
    if (t < 512) v[(size_t)b * 512 + t] = vv[t];
}

// sup loss; computes u_i on the fly: u_i*512 = 1/(K@v)_i.
__global__ __launch_bounds__(256) void sup_kernel(
    const unsigned short* __restrict__ Kb16, const float* __restrict__ v,
    const float* __restrict__ rel, const float* __restrict__ pa,
    float* __restrict__ acc) {
    const int b = blockIdx.x >> 6;
    const int rg = blockIdx.x & 63;
    const int t = threadIdx.x;
    const int h = t >> 5;
    const int c = t & 31;
    const int row = rg * 8 + h;
    const unsigned int* kp =
        (const unsigned int*)(Kb16 + ((size_t)b * 512 + row) * 512 + c * 16);
    uint4 kw0 = *(const uint4*)(kp);
    uint4 kw1 = *(const uint4*)(kp + 4);
    float k[16];
    unpack8(kw0, k); unpack8(kw1, k + 8);
    float vr[16];
    *(f32x4*)&vr[0]  = *(const f32x4*)&v[b * 512 + c * 16];
    *(f32x4*)&vr[4]  = *(const f32x4*)&v[b * 512 + c * 16 + 4];
    *(f32x4*)&vr[8]  = *(const f32x4*)&v[b * 512 + c * 16 + 8];
    *(f32x4*)&vr[12] = *(const f32x4*)&v[b * 512 + c * 16 + 12];
    float rs = 0.f;
#pragma unroll
    for (int e = 0; e < 16; ++e) rs = fmaf(k[e], vr[e], rs);
#pragma unroll
    for (int off = 16; off > 0; off >>= 1) rs += __shfl_xor(rs, off, 32);
    float inv = 1.f / rs;
    float part = 0.f;
    const float* rp = &rel[((size_t)b * 512 + row) * 512 + c * 16];
#pragma unroll
    for (int e = 0; e < 16; e += 4) {
        float4 r4 = *(const float4*)(rp + e);
        float d0 = k[e]     * vr[e]     * inv - r4.x;
        float d1 = k[e + 1] * vr[e + 1] * inv - r4.y;
        float d2 = k[e + 2] * vr[e + 2] * inv - r4.z;
        float d3 = k[e + 3] * vr[e + 3] * inv - r4.w;
        part += d0 * d0 + d1 * d1 + d2 * d2 + d3 * d3;
    }
    part *= pa[b * 512 + row];
    float tot = block_reduce_256(part);
    if (t == 0) atomicAdd(&acc[ACC_SUP + (blockIdx.x & 255)], tot);
}

__global__ __launch_bounds__(256) void final_kernel(const float* __restrict__ acc,
                                                    float* __restrict__ out) {
    int t = threadIdx.x;
    float vin = (t < 64) ? acc[ACC_IN + t] : 0.f;
    float sIn = block_reduce_256(vin);
    float vsup = acc[ACC_SUP + t];
    float sSup = block_reduce_256(vsup);
    if (t == 0)
        out[0] = sIn * (1.f / 16777216.f) + 10.f * sSup / acc[ACC_PA];
}

extern "C" void kernel_launch(void* const* d_in, const int* in_sizes, int n_in,
                              void* d_out, int out_size, void* d_ws, size_t ws_size,
                              hipStream_t stream) {
    const float* la  = (const float*)d_in[0];
    const float* lb  = (const float*)d_in[1];
    const float* xA  = (const float*)d_in[2];
    const float* xB  = (const float*)d_in[3];
    const float* rel = (const float*)d_in[4];
    const float* pa  = (const float*)d_in[5];
    const float* pb  = (const float*)d_in[6];
    const float* W1  = (const float*)d_in[7];
    const float* b1  = (const float*)d_in[8];
    const float* g1  = (const float*)d_in[9];
    const float* be1 = (const float*)d_in[10];
    const float* W2  = (const float*)d_in[11];
    const float* b2  = (const float*)d_in[12];
    const float* g2  = (const float*)d_in[13];
    const float* be2 = (const float*)d_in[14];
    float* out = (float*)d_out;

    float* ws = (float*)d_ws;
    unsigned short* Kb16 = (unsigned short*)(ws + KB_OFF);   // Ybf1/Ybf2 then K
    unsigned short* Xbf  = (unsigned short*)(ws + X_OFF);    // Xbf then Ebf
    unsigned short* Hbf  = (unsigned short*)(ws + H_OFF);
    float* norms = ws + NORM_OFF;
    float* u     = ws + U_OFF;    // colsum staging
    float* v     = ws + V_OFF;
    int* argA    = (int*)(ws + ARGA_OFF);
    int* argB    = (int*)(ws + ARGB_OFF);
    float* acc   = ws + ACC_OFF;
    unsigned short* Wt1 = (unsigned short*)(ws + WT1_OFF);
    unsigned short* Wt2 = (unsigned short*)(ws + WT2_OFF);

    zero_acc_kernel<<<128, 256, 0, stream>>>(acc, u);        // zero acc + colsum
    argmax_pa_kernel<<<128, 256, 0, stream>>>(la, lb, pa, argA, argB, acc);

    // casts
    cast_bf_kernel<<<2048, 256, 0, stream>>>(xA, Xbf);
    cast_bf_kernel<<<2048, 256, 0, stream>>>(xB, Xbf + (size_t)MROWS * DIM);
    cast_wt_kernel<<<dim3(16, 16), 256, 0, stream>>>(W1, Wt1);
    cast_wt_kernel<<<dim3(16, 16), 256, 0, stream>>>(W2, Wt2);

    // layer 1
    gemm_bf_kernel<<<dim3(1024, 4), 256, 0, stream>>>(Xbf, Wt1, Kb16);
    ln_bf_kernel<<<16384, 256, 0, stream>>>(Kb16, Hbf, b1, g1, be1, nullptr);
    // layer 2
    gemm_bf_kernel<<<dim3(1024, 4), 256, 0, stream>>>(Hbf, Wt2, Kb16);
    ln_bf_kernel<<<16384, 256, 0, stream>>>(Kb16, Xbf, b2, g2, be2, norms);  // Ebf -> Xbf buf

    // cost + K (bf16) + column sums: 512 panel blocks x 512 threads
    cost_mfma_kernel<<<512, 512, 0, stream>>>(Xbf, norms, argA, argB, pa, pb,
                                              Kb16, acc, u);

    // sinkhorn: 9 fused K-passes (pass-0 in cost, final u-pass in sup)
    sinkhorn_kernel<<<64, 1024, 0, stream>>>(Kb16, u, v);

    sup_kernel<<<4096, 256, 0, stream>>>(Kb16, v, rel, pa, acc);
    final_kernel<<<1, 256, 0, stream>>>(acc, out);
}

// Round 11
// 363.325 us; speedup vs baseline: 1.1566x; 1.0645x over previous
//
#include <hip/hip_runtime.h>
#include <math.h>

// Problem constants
#define BSZ 64
#define NPTS 512
#define DIM 256
#define MROWS 32768      // BSZ*NPTS
#define TOTROWS 65536
#define BIGF 1.0e9f

typedef __bf16 bf16x8 __attribute__((ext_vector_type(8)));
typedef float  f32x4  __attribute__((ext_vector_type(4)));
typedef __attribute__((address_space(1))) const void* as1cv;
typedef __attribute__((address_space(3))) void* as3v;

// ws layout (float offsets)
#define KB_OFF    0ull          // ushort[16777216]: K(bf16)
#define X_OFF     8388608ull    // ushort[16777216]: Xbf -> Ebf
#define H_OFF     16777216ull   // ushort[16777216]: Hbf
#define NORM_OFF  25165824ull   // 65536 f32
#define U_OFF     25231360ull   // 32768 f32 (colsum staged here pre-sinkhorn)
#define V_OFF     25264128ull   // 32768 f32
#define ARGA_OFF  25296896ull   // 32768 int
#define ARGB_OFF  25329664ull   // 32768 int
#define ACC_OFF   25362432ull   // 512 f32
#define WT1_OFF   25362944ull   // ushort[65536]
#define WT2_OFF   25395712ull   // ushort[65536]

#define ACC_PA   0
#define ACC_IN   1     // 64 slots
#define ACC_SUP  65    // 256 slots
#define ACC_CNT  321

__device__ __forceinline__ float bf2f(unsigned short h) {
    return __uint_as_float(((unsigned int)h) << 16);
}
__device__ __forceinline__ unsigned short f2bf(float f) {
    unsigned int u = __float_as_uint(f);
    u = (u + 0x7FFFu + ((u >> 16) & 1u)) >> 16;
    return (unsigned short)u;
}

// re-entrant, 256-thread blocks only
__device__ __forceinline__ float block_reduce_256(float val) {
    __shared__ float sh[4];
    int lane = threadIdx.x & 63;
    int wv = threadIdx.x >> 6;
    __syncthreads();
#pragma unroll
    for (int off = 32; off > 0; off >>= 1) val += __shfl_down(val, off, 64);
    if (lane == 0) sh[wv] = val;
    __syncthreads();
    float r = 0.f;
    if (wv == 0 && lane < 4) r = sh[lane];
    if (wv == 0) {
        r += __shfl_down(r, 2, 64);
        r += __shfl_down(r, 1, 64);
    }
    return r;  // valid in thread 0
}

__device__ __forceinline__ void unpack8(uint4 w, float* k) {
    k[0] = __uint_as_float(w.x << 16);
    k[1] = __uint_as_float(w.x & 0xFFFF0000u);
    k[2] = __uint_as_float(w.y << 16);
    k[3] = __uint_as_float(w.y & 0xFFFF0000u);
    k[4] = __uint_as_float(w.z << 16);
    k[5] = __uint_as_float(w.z & 0xFFFF0000u);
    k[6] = __uint_as_float(w.w << 16);
    k[7] = __uint_as_float(w.w & 0xFFFF0000u);
}
__device__ __forceinline__ float dot8(const float* k, const float* vr) {
    float rs = k[0] * vr[0];
    rs = fmaf(k[1], vr[1], rs); rs = fmaf(k[2], vr[2], rs);
    rs = fmaf(k[3], vr[3], rs); rs = fmaf(k[4], vr[4], rs);
    rs = fmaf(k[5], vr[5], rs); rs = fmaf(k[6], vr[6], rs);
    return fmaf(k[7], vr[7], rs);
}

// Packed 4-row all-lanes reduce: rows A,B,C,D per-lane partials -> row sums,
// replicated within 16-lane groups: g0=A, g1=C, g2=B, g3=D. 10 DS ops for 4 rows.
__device__ __forceinline__ float packed_reduce4(float p0, float p1, float p2, float p3, int l) {
    p0 += __shfl_xor(p0, 32, 64);
    p1 += __shfl_xor(p1, 32, 64);
    p2 += __shfl_xor(p2, 32, 64);
    p3 += __shfl_xor(p3, 32, 64);
    float m1 = (l & 32) ? p1 : p0;
    float m2 = (l & 32) ? p3 : p2;
    m1 += __shfl_xor(m1, 16, 64);
    m2 += __shfl_xor(m2, 16, 64);
    float s = (l & 16) ? m2 : m1;
    s += __shfl_xor(s, 8, 64);
    s += __shfl_xor(s, 4, 64);
    s += __shfl_xor(s, 2, 64);
    s += __shfl_xor(s, 1, 64);
    return s;
}
__device__ __forceinline__ float bcast_lane(float x, int lane) {
    return __uint_as_float((unsigned)__builtin_amdgcn_readlane((int)__float_as_uint(x), lane));
}

__global__ void zero_acc_kernel(float* acc, float* colsum) {
    int t = blockIdx.x * 256 + threadIdx.x;   // grid 128*256 = 32768
    if (t < 512) acc[t] = 0.f;
    colsum[t] = 0.f;
}

__global__ __launch_bounds__(256) void argmax_pa_kernel(
    const float* __restrict__ la, const float* __restrict__ lb,
    const float* __restrict__ pa, int* __restrict__ argA, int* __restrict__ argB,
    float* __restrict__ acc) {
    int i = blockIdx.x * 256 + threadIdx.x;
    float4 a = *(const float4*)&la[(size_t)i * 4];
    float av[4] = {a.x, a.y, a.z, a.w};
    int ba = 0; float bv = av[0];
#pragma unroll
    for (int c = 1; c < 4; ++c) if (av[c] > bv) { bv = av[c]; ba = c; }
    argA[i] = ba;
    float4 b = *(const float4*)&lb[(size_t)i * 4];
    float bw[4] = {b.x, b.y, b.z, b.w};
    int bbi = 0; float bm = bw[0];
#pragma unroll
    for (int c = 1; c < 4; ++c) if (bw[c] > bm) { bm = bw[c]; bbi = c; }
    argB[i] = bbi;
    float p = pa[i];
#pragma unroll
    for (int off = 32; off > 0; off >>= 1) p += __shfl_down(p, off, 64);
    if ((threadIdx.x & 63) == 0) atomicAdd(&acc[ACC_PA], p);
}

// f32 -> bf16 bulk cast; grid 2048x256, 4 float4-groups/thread
__global__ __launch_bounds__(256) void cast_bf_kernel(
    const float* __restrict__ src, unsigned short* __restrict__ dst) {
    int tid = blockIdx.x * 256 + threadIdx.x;      // < 524288
#pragma unroll
    for (int k = 0; k < 4; ++k) {
        int i4 = tid + k * 524288;                 // < 2097152
        float4 v = *(const float4*)&src[(size_t)i4 * 4];
        ushort4 o;
        o.x = f2bf(v.x); o.y = f2bf(v.y); o.z = f2bf(v.z); o.w = f2bf(v.w);
        *(ushort4*)&dst[(size_t)i4 * 4] = o;
    }
}

// W[256][256] f32 -> Wt[n][k] bf16 (transposed)
__global__ __launch_bounds__(256) void cast_wt_kernel(
    const float* __restrict__ W, unsigned short* __restrict__ Wt) {
    __shared__ float tile[16][17];
    int tx = threadIdx.x & 15, ty = threadIdx.x >> 4;
    int bx = blockIdx.x, by = blockIdx.y;
    tile[ty][tx] = W[(size_t)(by * 16 + ty) * 256 + bx * 16 + tx];
    __syncthreads();
    Wt[(size_t)(bx * 16 + ty) * 256 + by * 16 + tx] = f2bf(tile[tx][ty]);
}

// Fused GEMM + bias + leaky + LayerNorm. One persistent block per 256 rows:
// Wt (256x256 bf16 = 128KB) staged ONCE via global_load_lds (seg XOR swizzle);
// A fragments loaded straight global->VGPR (each row used by exactly one wave);
// LN applied in-register on the f32 accumulator; optional rounded row-norms.
// 256 blocks x 512 threads (8 waves, 2/SIMD). 2 panel-iterations of 128 rows.
__global__ __launch_bounds__(512) void gemmln_kernel(
    const unsigned short* __restrict__ X, const unsigned short* __restrict__ Wt,
    const float* __restrict__ bias, const float* __restrict__ gam,
    const float* __restrict__ bet,
    unsigned short* __restrict__ Yout, float* __restrict__ norms) {
    __shared__ unsigned short Ws[256 * 256];   // 128 KB, row = n, 512B, swizzled
    const int t = threadIdx.x;
    const int L = t & 63, wv = t >> 6;
    const int q = L >> 4, n = L & 15;
    // stage Wt once: wave wv stages rows wv*32 .. +32 (2 rows per instr)
    {
        const int lrow = L >> 5, segp = L & 31;
#pragma unroll
        for (int j = 0; j < 16; ++j) {
            int row = wv * 32 + 2 * j + lrow;
            int sseg = segp ^ (row & 7);
            __builtin_amdgcn_global_load_lds((as1cv)&Wt[(size_t)row * 256 + sseg * 8],
                                             (as3v)&Ws[(wv * 32 + 2 * j) * 256], 16, 0, 0);
        }
    }
    // per-col params: col = nt*16 + n
    float bcol[16], gcol[16], ecol[16];
#pragma unroll
    for (int nt = 0; nt < 16; ++nt) {
        bcol[nt] = bias[nt * 16 + n];
        gcol[nt] = gam[nt * 16 + n];
        ecol[nt] = bet[nt * 16 + n];
    }
    __syncthreads();   // Wt staged

    const int sw = n & 7;
    for (int p = 0; p < 2; ++p) {
        const size_t row0 = (size_t)blockIdx.x * 256 + p * 128 + wv * 16;
        // A fragments: m = lane&15 -> row row0+n ; k-chunk = ks*32 + q*8
        bf16x8 a[8];
#pragma unroll
        for (int ks = 0; ks < 8; ++ks)
            a[ks] = *(const bf16x8*)&X[(row0 + n) * 256 + ks * 32 + q * 8];
        f32x4 acc[16];
#pragma unroll
        for (int nt = 0; nt < 16; ++nt) acc[nt] = (f32x4){0.f, 0.f, 0.f, 0.f};
#pragma unroll
        for (int nt = 0; nt < 16; ++nt) {
#pragma unroll
            for (int ks = 0; ks < 8; ++ks) {
                bf16x8 bv = *(const bf16x8*)&Ws[(nt * 16 + n) * 256 +
                                                (((ks * 4 + q) ^ sw) * 8)];
                acc[nt] = __builtin_amdgcn_mfma_f32_16x16x32_bf16(a[ks], bv, acc[nt], 0, 0, 0);
            }
        }
        // epilogue: output row = row0 + q*4 + r, col = nt*16 + n.
        // bias + leaky, then 16-lane-group LN stats (lanes share rows when q fixed).
        float mean4[4], inv4[4];
#pragma unroll
        for (int r = 0; r < 4; ++r) {
            float s = 0.f, sq = 0.f;
#pragma unroll
            for (int nt = 0; nt < 16; ++nt) {
                float h = acc[nt][r] + bcol[nt];
                h = h >= 0.f ? h : 0.01f * h;
                acc[nt][r] = h;
                s += h; sq += h * h;
            }
#pragma unroll
            for (int m = 1; m < 16; m <<= 1) {
                s += __shfl_xor(s, m, 64);
                sq += __shfl_xor(sq, m, 64);
            }
            float mean = s * (1.f / 256.f);
            float var = fmaxf(sq * (1.f / 256.f) - mean * mean, 0.f);
            mean4[r] = mean;
            inv4[r] = rsqrtf(var + 1e-5f);
        }
        float nr[4] = {0.f, 0.f, 0.f, 0.f};
#pragma unroll
        for (int nt = 0; nt < 16; ++nt) {
#pragma unroll
            for (int r = 0; r < 4; ++r) {
                float o = (acc[nt][r] - mean4[r]) * inv4[r] * gcol[nt] + ecol[nt];
                unsigned short ob = f2bf(o);
                float of = bf2f(ob);
                nr[r] += of * of;
                Yout[(row0 + q * 4 + r) * 256 + nt * 16 + n] = ob;
            }
        }
        if (norms) {
#pragma unroll
            for (int r = 0; r < 4; ++r) {
#pragma unroll
                for (int m = 1; m < 16; m <<= 1) nr[r] += __shfl_xor(nr[r], m, 64);
                if (n == 0) norms[row0 + q * 4 + r] = nr[r];
            }
        }
    }
}

// Panel cost kernel: block = (batch b, 64-row panel i0). 512 threads (8 waves).
// Stage A once; loop over 8 B column-tiles, double-buffered global_load_lds.
__global__ __launch_bounds__(512) void cost_mfma_kernel(
    const unsigned short* __restrict__ E, const float* __restrict__ norms,
    const int* __restrict__ argA, const int* __restrict__ argB,
    const float* __restrict__ pa, const float* __restrict__ pb,
    unsigned short* __restrict__ Kb16, float* __restrict__ acc,
    float* __restrict__ colsum) {
    __shared__ unsigned short As[64 * 256];       // 32 KB
    __shared__ unsigned short Bs[2][64 * 256];    // 64 KB
    __shared__ float cswave[8][256];              // 8 KB per-wave colsum partials
    __shared__ float redp[8];
    const int t = threadIdx.x;
    const int L = t & 63, wv = t >> 6;
    const int q = L >> 4, n = L & 15;
    const int rh = wv & 3, ch = wv >> 2;
    // b = id&63 so a batch's 8 panels share an XCD (id%8 == b%8)
    const int b = blockIdx.x & 63;
    const int i0 = (blockIdx.x >> 6) * 64;
    const unsigned short* eA = E + (size_t)b * 512 * 256;
    const unsigned short* eB = E + (size_t)(32768 + b * 512) * 256;
    const int lrow = L >> 5, segp = L & 31;

#pragma unroll
    for (int jj = 0; jj < 4; ++jj) {
        int row = wv * 8 + 2 * jj + lrow;
        int sseg = segp ^ (row & 7);
        __builtin_amdgcn_global_load_lds((as1cv)&eA[(size_t)(i0 + row) * 256 + sseg * 8],
                                         (as3v)&As[(wv * 8 + 2 * jj) * 256], 16, 0, 0);
        __builtin_amdgcn_global_load_lds((as1cv)&eB[(size_t)row * 256 + sseg * 8],
                                         (as3v)&Bs[0][(wv * 8 + 2 * jj) * 256], 16, 0, 0);
    }
    const int base_row = i0 + rh * 16 + q * 4;
    float nA[4], pAr[4]; int cA[4];
#pragma unroll
    for (int rr = 0; rr < 4; ++rr) {
        nA[rr] = norms[b * 512 + base_row + rr];
        pAr[rr] = pa[b * 512 + base_row + rr];
        cA[rr] = argA[b * 512 + base_row + rr];
    }
    float part = 0.f;
    __syncthreads();   // A + B0 staged

    const int rowa = rh * 16 + n;
    const int sw = n & 7;
    bf16x8 areg[8];
#pragma unroll
    for (int c = 0; c < 8; ++c)
        areg[c] = *(const bf16x8*)&As[rowa * 256 + (((c * 4 + q) ^ sw) * 8)];

    for (int j = 0; j < 8; ++j) {
        const int cur = j & 1;
        if (j < 7) {
#pragma unroll
            for (int jj = 0; jj < 4; ++jj) {
                int row = wv * 8 + 2 * jj + lrow;
                int sseg = segp ^ (row & 7);
                __builtin_amdgcn_global_load_lds(
                    (as1cv)&eB[(size_t)((j + 1) * 64 + row) * 256 + sseg * 8],
                    (as3v)&Bs[cur ^ 1][(wv * 8 + 2 * jj) * 256], 16, 0, 0);
            }
        }
        f32x4 dot[2];
        dot[0] = (f32x4){0.f, 0.f, 0.f, 0.f};
        dot[1] = (f32x4){0.f, 0.f, 0.f, 0.f};
#pragma unroll
        for (int c = 0; c < 8; ++c) {
#pragma unroll
            for (int np = 0; np < 2; ++np) {
                int nt = ch * 2 + np;
                bf16x8 bv = *(const bf16x8*)&Bs[cur][(nt * 16 + n) * 256 +
                                                     (((c * 4 + q) ^ sw) * 8)];
                dot[np] = __builtin_amdgcn_mfma_f32_16x16x32_bf16(areg[c], bv, dot[np], 0, 0, 0);
            }
        }
#pragma unroll
        for (int np = 0; np < 2; ++np) {
            int nt = ch * 2 + np;
            int col = j * 64 + nt * 16 + n;
            float nB = norms[32768 + b * 512 + col];
            float pB = pb[b * 512 + col];
            int cB = argB[b * 512 + col];
            float cloc = 0.f;
#pragma unroll
            for (int rr = 0; rr < 4; ++rr) {
                float d2 = nA[rr] + nB - 2.f * dot[np][rr];
                float c = sqrtf(fmaxf(d2, 0.f));
                float pm = pAr[rr] * pB;
                float cc = c + (BIGF - BIGF * pm);
                float sgn = (cA[rr] == cB) ? 1.f : -1.f;
                part += cc * sgn * pm;
                unsigned short kb = f2bf(expf(-2.f * cc));
                Kb16[((size_t)b * 512 + base_row + rr) * 512 + col] = kb;
                cloc += bf2f(kb);
            }
            cloc += __shfl_xor(cloc, 16, 64);
            cloc += __shfl_xor(cloc, 32, 64);
            if (L < 16) cswave[wv][j * 32 + np * 16 + L] = cloc;
        }
        __syncthreads();
    }

    {
        float pw = part;
#pragma unroll
        for (int off = 32; off > 0; off >>= 1) pw += __shfl_down(pw, off, 64);
        if (L == 0) redp[wv] = pw;
    }
    __syncthreads();
    {
        int c = t & 511;
        int local = ((c >> 6) << 5) | (c & 31);
        int cch = (c >> 5) & 1;
        float s = cswave[4 * cch][local] + cswave[4 * cch + 1][local] +
                  cswave[4 * cch + 2][local] + cswave[4 * cch + 3][local];
        atomicAdd(&colsum[(size_t)b * 512 + c], s);
    }
    if (t == 0) {
        float s = 0.f;
#pragma unroll
        for (int k = 0; k < 8; ++k) s += redp[k];
        atomicAdd(&acc[ACC_IN + b], s);
    }
}

// Fused Sinkhorn: 9 fused passes (pass-0 folded into cost via colsum;
// final u-pass folded into sup). Writes v only.
__global__ __launch_bounds__(1024) void sinkhorn_kernel(
    const unsigned short* __restrict__ Kb16, const float* __restrict__ colsum,
    float* __restrict__ v) {
    const int b = blockIdx.x;
    const unsigned short* Kb = Kb16 + (size_t)b * 262144;
    __shared__ float vv[512];
    __shared__ float cp[16][512];
    const int t = threadIdx.x, wv = t >> 6, l = t & 63;
    const unsigned short* base = Kb + (size_t)(wv * 32) * 512 + l * 8;

    if (t < 512) vv[t] = 1.f / colsum[(size_t)b * 512 + t];
    __syncthreads();

    for (int it = 1; it <= 9; ++it) {
        float vr[8];
        *(f32x4*)&vr[0] = *(const f32x4*)&vv[l * 8];
        *(f32x4*)&vr[4] = *(const f32x4*)&vv[l * 8 + 4];
        float cs[8];
#pragma unroll
        for (int e = 0; e < 8; ++e) cs[e] = 0.f;
#pragma unroll 2
        for (int g = 0; g < 8; ++g) {
            const unsigned short* gb = base + (size_t)(g * 4) * 512;
            uint4 w0 = *(const uint4*)(gb);
            uint4 w1 = *(const uint4*)(gb + 512);
            uint4 w2 = *(const uint4*)(gb + 1024);
            uint4 w3 = *(const uint4*)(gb + 1536);
            float k0[8], k1[8], k2[8], k3[8];
            unpack8(w0, k0); unpack8(w1, k1); unpack8(w2, k2); unpack8(w3, k3);
            float p0 = dot8(k0, vr);
            float p1 = dot8(k1, vr);
            float p2 = dot8(k2, vr);
            float p3 = dot8(k3, vr);
            float s = packed_reduce4(p0, p1, p2, p3, l);
            float us = 0.001953125f * __builtin_amdgcn_rcpf(s);
            float uA = bcast_lane(us, 0);
            float uC = bcast_lane(us, 16);
            float uB = bcast_lane(us, 32);
            float uD = bcast_lane(us, 48);
#pragma unroll
            for (int e = 0; e < 8; ++e) {
                float c = fmaf(k0[e], uA, cs[e]);
                c = fmaf(k1[e], uB, c);
                c = fmaf(k2[e], uC, c);
                cs[e] = fmaf(k3[e], uD, c);
            }
        }
        *(f32x4*)&cp[wv][l * 8]     = *(f32x4*)&cs[0];
        *(f32x4*)&cp[wv][l * 8 + 4] = *(f32x4*)&cs[4];
        __syncthreads();
        if (t < 512) {
            float ss = 0.f;
#pragma unroll
            for (int k = 0; k < 16; ++k) ss += cp[k][t];
            vv[t] = (1.f / 512.f) / ss;
        }
        __syncthreads();
    }
    if (t < 512) v[(size_t)b * 512 + t] = vv[t];
}

// sup loss; computes u_i on the fly: u_i*512 = 1/(K@v)_i.
__global__ __launch_bounds__(256) void sup_kernel(
    const unsigned short* __restrict__ Kb16, const float* __restrict__ v,
    const float* __restrict__ rel, const float* __restrict__ pa,
    float* __restrict__ acc) {
    const int b = blockIdx.x >> 6;
    const int rg = blockIdx.x & 63;
    const int t = threadIdx.x;
    const int h = t >> 5;
    const int c = t & 31;
    const int row = rg * 8 + h;
    const unsigned int* kp =
        (const unsigned int*)(Kb16 + ((size_t)b * 512 + row) * 512 + c * 16);
    uint4 kw0 = *(const uint4*)(kp);
    uint4 kw1 = *(const uint4*)(kp + 4);
    float k[16];
    unpack8(kw0, k); unpack8(kw1, k + 8);
    float vr[16];
    *(f32x4*)&vr[0]  = *(const f32x4*)&v[b * 512 + c * 16];
    *(f32x4*)&vr[4]  = *(const f32x4*)&v[b * 512 + c * 16 + 4];
    *(f32x4*)&vr[8]  = *(const f32x4*)&v[b * 512 + c * 16 + 8];
    *(f32x4*)&vr[12] = *(const f32x4*)&v[b * 512 + c * 16 + 12];
    float rs = 0.f;
#pragma unroll
    for (int e = 0; e < 16; ++e) rs = fmaf(k[e], vr[e], rs);
#pragma unroll
    for (int off = 16; off > 0; off >>= 1) rs += __shfl_xor(rs, off, 32);
    float inv = 1.f / rs;
    float part = 0.f;
    const float* rp = &rel[((size_t)b * 512 + row) * 512 + c * 16];
#pragma unroll
    for (int e = 0; e < 16; e += 4) {
        float4 r4 = *(const float4*)(rp + e);
        float d0 = k[e]     * vr[e]     * inv - r4.x;
        float d1 = k[e + 1] * vr[e + 1] * inv - r4.y;
        float d2 = k[e + 2] * vr[e + 2] * inv - r4.z;
        float d3 = k[e + 3] * vr[e + 3] * inv - r4.w;
        part += d0 * d0 + d1 * d1 + d2 * d2 + d3 * d3;
    }
    part *= pa[b * 512 + row];
    float tot = block_reduce_256(part);
    if (t == 0) atomicAdd(&acc[ACC_SUP + (blockIdx.x & 255)], tot);
}

__global__ __launch_bounds__(256) void final_kernel(const float* __restrict__ acc,
                                                    float* __restrict__ out) {
    int t = threadIdx.x;
    float vin = (t < 64) ? acc[ACC_IN + t] : 0.f;
    float sIn = block_reduce_256(vin);
    float vsup = acc[ACC_SUP + t];
    float sSup = block_reduce_256(vsup);
    if (t == 0)
        out[0] = sIn * (1.f / 16777216.f) + 10.f * sSup / acc[ACC_PA];
}

extern "C" void kernel_launch(void* const* d_in, const int* in_sizes, int n_in,
                              void* d_out, int out_size, void* d_ws, size_t ws_size,
                              hipStream_t stream) {
    const float* la  = (const float*)d_in[0];
    const float* lb  = (const float*)d_in[1];
    const float* xA  = (const float*)d_in[2];
    const float* xB  = (const float*)d_in[3];
    const float* rel = (const float*)d_in[4];
    const float* pa  = (const float*)d_in[5];
    const float* pb  = (const float*)d_in[6];
    const float* W1  = (const float*)d_in[7];
    const float* b1  = (const float*)d_in[8];
    const float* g1  = (const float*)d_in[9];
    const float* be1 = (const float*)d_in[10];
    const float* W2  = (const float*)d_in[11];
    const float* b2  = (const float*)d_in[12];
    const float* g2  = (const float*)d_in[13];
    const float* be2 = (const float*)d_in[14];
    float* out = (float*)d_out;

    float* ws = (float*)d_ws;
    unsigned short* Kb16 = (unsigned short*)(ws + KB_OFF);
    unsigned short* Xbf  = (unsigned short*)(ws + X_OFF);    // Xbf then Ebf
    unsigned short* Hbf  = (unsigned short*)(ws + H_OFF);
    float* norms = ws + NORM_OFF;
    float* u     = ws + U_OFF;    // colsum staging
    float* v     = ws + V_OFF;
    int* argA    = (int*)(ws + ARGA_OFF);
    int* argB    = (int*)(ws + ARGB_OFF);
    float* acc   = ws + ACC_OFF;
    unsigned short* Wt1 = (unsigned short*)(ws + WT1_OFF);
    unsigned short* Wt2 = (unsigned short*)(ws + WT2_OFF);

    zero_acc_kernel<<<128, 256, 0, stream>>>(acc, u);        // zero acc + colsum
    argmax_pa_kernel<<<128, 256, 0, stream>>>(la, lb, pa, argA, argB, acc);

    // casts
    cast_bf_kernel<<<2048, 256, 0, stream>>>(xA, Xbf);
    cast_bf_kernel<<<2048, 256, 0, stream>>>(xB, Xbf + (size_t)MROWS * DIM);
    cast_wt_kernel<<<dim3(16, 16), 256, 0, stream>>>(W1, Wt1);
    cast_wt_kernel<<<dim3(16, 16), 256, 0, stream>>>(W2, Wt2);

    // fused layer 1 and layer 2 (GEMM + bias + leaky + LN [+ norms])
    gemmln_kernel<<<256, 512, 0, stream>>>(Xbf, Wt1, b1, g1, be1, Hbf, nullptr);
    gemmln_kernel<<<256, 512, 0, stream>>>(Hbf, Wt2, b2, g2, be2, Xbf, norms);

    // cost + K (bf16) + column sums: 512 panel blocks x 512 threads
    cost_mfma_kernel<<<512, 512, 0, stream>>>(Xbf, norms, argA, argB, pa, pb,
                                              Kb16, acc, u);

    // sinkhorn: 9 fused K-passes (pass-0 in cost, final u-pass in sup)
    sinkhorn_kernel<<<64, 1024, 0, stream>>>(Kb16, u, v);

    sup_kernel<<<4096, 256, 0, stream>>>(Kb16, v, rel, pa, acc);
    final_kernel<<<1, 256, 0, stream>>>(acc, out);
}

// Round 12
// 335.456 us; speedup vs baseline: 1.2527x; 1.0831x over previous
//
#include <hip/hip_runtime.h>
#include <math.h>

// Problem constants
#define BSZ 64
#define NPTS 512
#define DIM 256
#define MROWS 32768      // BSZ*NPTS
#define TOTROWS 65536
#define BIGF 1.0e9f

typedef __bf16 bf16x8 __attribute__((ext_vector_type(8)));
typedef float  f32x4  __attribute__((ext_vector_type(4)));
typedef __attribute__((address_space(1))) const void* as1cv;
typedef __attribute__((address_space(3))) void* as3v;

// ws layout (float offsets)
#define KB_OFF    0ull          // ushort[16777216]: K(bf16)
#define X_OFF     8388608ull    // ushort[16777216]: Ebf (layer-2 output)
#define H_OFF     16777216ull   // ushort[16777216]: Hbf
#define NORM_OFF  25165824ull   // 65536 f32
#define U_OFF     25231360ull   // 32768 f32 (colsum staged here pre-sinkhorn)
#define V_OFF     25264128ull   // 32768 f32
#define ARGA_OFF  25296896ull   // 32768 int
#define ARGB_OFF  25329664ull   // 32768 int
#define ACC_OFF   25362432ull   // 512 f32
#define WT1_OFF   25362944ull   // ushort[65536]
#define WT2_OFF   25395712ull   // ushort[65536]

#define ACC_PA   0
#define ACC_IN   1     // 64 slots
#define ACC_SUP  65    // 256 slots
#define ACC_CNT  321

__device__ __forceinline__ float bf2f(unsigned short h) {
    return __uint_as_float(((unsigned int)h) << 16);
}
__device__ __forceinline__ unsigned short f2bf(float f) {
    unsigned int u = __float_as_uint(f);
    u = (u + 0x7FFFu + ((u >> 16) & 1u)) >> 16;
    return (unsigned short)u;
}

// convert 8 consecutive f32 -> bf16x8 fragment (same f2bf RNE as the old cast)
__device__ __forceinline__ bf16x8 cvt8(const float* p) {
    float4 f0 = *(const float4*)p;
    float4 f1 = *(const float4*)(p + 4);
    union { unsigned short s[8]; bf16x8 v; } r;
    r.s[0] = f2bf(f0.x); r.s[1] = f2bf(f0.y); r.s[2] = f2bf(f0.z); r.s[3] = f2bf(f0.w);
    r.s[4] = f2bf(f1.x); r.s[5] = f2bf(f1.y); r.s[6] = f2bf(f1.z); r.s[7] = f2bf(f1.w);
    return r.v;
}

// re-entrant, 256-thread blocks only
__device__ __forceinline__ float block_reduce_256(float val) {
    __shared__ float sh[4];
    int lane = threadIdx.x & 63;
    int wv = threadIdx.x >> 6;
    __syncthreads();
#pragma unroll
    for (int off = 32; off > 0; off >>= 1) val += __shfl_down(val, off, 64);
    if (lane == 0) sh[wv] = val;
    __syncthreads();
    float r = 0.f;
    if (wv == 0 && lane < 4) r = sh[lane];
    if (wv == 0) {
        r += __shfl_down(r, 2, 64);
        r += __shfl_down(r, 1, 64);
    }
    return r;  // valid in thread 0
}

__device__ __forceinline__ void unpack8(uint4 w, float* k) {
    k[0] = __uint_as_float(w.x << 16);
    k[1] = __uint_as_float(w.x & 0xFFFF0000u);
    k[2] = __uint_as_float(w.y << 16);
    k[3] = __uint_as_float(w.y & 0xFFFF0000u);
    k[4] = __uint_as_float(w.z << 16);
    k[5] = __uint_as_float(w.z & 0xFFFF0000u);
    k[6] = __uint_as_float(w.w << 16);
    k[7] = __uint_as_float(w.w & 0xFFFF0000u);
}
__device__ __forceinline__ float dot8(const float* k, const float* vr) {
    float rs = k[0] * vr[0];
    rs = fmaf(k[1], vr[1], rs); rs = fmaf(k[2], vr[2], rs);
    rs = fmaf(k[3], vr[3], rs); rs = fmaf(k[4], vr[4], rs);
    rs = fmaf(k[5], vr[5], rs); rs = fmaf(k[6], vr[6], rs);
    return fmaf(k[7], vr[7], rs);
}

// Packed 4-row all-lanes reduce: rows A,B,C,D per-lane partials -> row sums,
// replicated within 16-lane groups: g0=A, g1=C, g2=B, g3=D. 10 DS ops for 4 rows.
__device__ __forceinline__ float packed_reduce4(float p0, float p1, float p2, float p3, int l) {
    p0 += __shfl_xor(p0, 32, 64);
    p1 += __shfl_xor(p1, 32, 64);
    p2 += __shfl_xor(p2, 32, 64);
    p3 += __shfl_xor(p3, 32, 64);
    float m1 = (l & 32) ? p1 : p0;
    float m2 = (l & 32) ? p3 : p2;
    m1 += __shfl_xor(m1, 16, 64);
    m2 += __shfl_xor(m2, 16, 64);
    float s = (l & 16) ? m2 : m1;
    s += __shfl_xor(s, 8, 64);
    s += __shfl_xor(s, 4, 64);
    s += __shfl_xor(s, 2, 64);
    s += __shfl_xor(s, 1, 64);
    return s;
}
__device__ __forceinline__ float bcast_lane(float x, int lane) {
    return __uint_as_float((unsigned)__builtin_amdgcn_readlane((int)__float_as_uint(x), lane));
}

__global__ void zero_acc_kernel(float* acc, float* colsum) {
    int t = blockIdx.x * 256 + threadIdx.x;   // grid 128*256 = 32768
    if (t < 512) acc[t] = 0.f;
    colsum[t] = 0.f;
}

__global__ __launch_bounds__(256) void argmax_pa_kernel(
    const float* __restrict__ la, const float* __restrict__ lb,
    const float* __restrict__ pa, int* __restrict__ argA, int* __restrict__ argB,
    float* __restrict__ acc) {
    int i = blockIdx.x * 256 + threadIdx.x;
    float4 a = *(const float4*)&la[(size_t)i * 4];
    float av[4] = {a.x, a.y, a.z, a.w};
    int ba = 0; float bv = av[0];
#pragma unroll
    for (int c = 1; c < 4; ++c) if (av[c] > bv) { bv = av[c]; ba = c; }
    argA[i] = ba;
    float4 b = *(const float4*)&lb[(size_t)i * 4];
    float bw[4] = {b.x, b.y, b.z, b.w};
    int bbi = 0; float bm = bw[0];
#pragma unroll
    for (int c = 1; c < 4; ++c) if (bw[c] > bm) { bm = bw[c]; bbi = c; }
    argB[i] = bbi;
    float p = pa[i];
#pragma unroll
    for (int off = 32; off > 0; off >>= 1) p += __shfl_down(p, off, 64);
    if ((threadIdx.x & 63) == 0) atomicAdd(&acc[ACC_PA], p);
}

// W[256][256] f32 -> Wt[n][k] bf16 (transposed)
__global__ __launch_bounds__(256) void cast_wt_kernel(
    const float* __restrict__ W, unsigned short* __restrict__ Wt) {
    __shared__ float tile[16][17];
    int tx = threadIdx.x & 15, ty = threadIdx.x >> 4;
    int bx = blockIdx.x, by = blockIdx.y;
    tile[ty][tx] = W[(size_t)(by * 16 + ty) * 256 + bx * 16 + tx];
    __syncthreads();
    Wt[(size_t)(bx * 16 + ty) * 256 + by * 16 + tx] = f2bf(tile[tx][ty]);
}

// Fused GEMM + bias + leaky + LayerNorm. One persistent block per 256 rows:
// Wt (256x256 bf16 = 128KB) staged ONCE via global_load_lds (seg XOR swizzle);
// A fragments loaded straight global->VGPR. Layer 1 (XfA/XfB non-null) reads
// the f32 inputs directly and converts in-register (identical f2bf RNE — the
// standalone cast kernels are eliminated). Layer 2 reads bf16 Hbf.
// LN applied in-register on the f32 accumulator; optional rounded row-norms.
// 256 blocks x 512 threads (8 waves, 2/SIMD). 2 panel-iterations of 128 rows.
__global__ __launch_bounds__(512) void gemmln_kernel(
    const float* __restrict__ XfA, const float* __restrict__ XfB,
    const unsigned short* __restrict__ Xb,
    const unsigned short* __restrict__ Wt,
    const float* __restrict__ bias, const float* __restrict__ gam,
    const float* __restrict__ bet,
    unsigned short* __restrict__ Yout, float* __restrict__ norms) {
    __shared__ unsigned short Ws[256 * 256];   // 128 KB, row = n, 512B, swizzled
    const int t = threadIdx.x;
    const int L = t & 63, wv = t >> 6;
    const int q = L >> 4, n = L & 15;
    // stage Wt once: wave wv stages rows wv*32 .. +32 (2 rows per instr)
    {
        const int lrow = L >> 5, segp = L & 31;
#pragma unroll
        for (int j = 0; j < 16; ++j) {
            int row = wv * 32 + 2 * j + lrow;
            int sseg = segp ^ (row & 7);
            __builtin_amdgcn_global_load_lds((as1cv)&Wt[(size_t)row * 256 + sseg * 8],
                                             (as3v)&Ws[(wv * 32 + 2 * j) * 256], 16, 0, 0);
        }
    }
    // per-col params: col = nt*16 + n
    float bcol[16], gcol[16], ecol[16];
#pragma unroll
    for (int nt = 0; nt < 16; ++nt) {
        bcol[nt] = bias[nt * 16 + n];
        gcol[nt] = gam[nt * 16 + n];
        ecol[nt] = bet[nt * 16 + n];
    }
    __syncthreads();   // Wt staged

    const int sw = n & 7;
    for (int p = 0; p < 2; ++p) {
        const size_t row0 = (size_t)blockIdx.x * 256 + p * 128 + wv * 16;
        // A fragments: lane group m = lane&15 -> row row0+n ; k-chunk = ks*32 + q*8
        bf16x8 a[8];
        if (XfA) {
            const float* Xf = (blockIdx.x < 128) ? XfA : XfB;
            const size_t lrow = ((size_t)(blockIdx.x & 127)) * 256 + p * 128 + wv * 16 + n;
            const float* xr = &Xf[lrow * 256];
#pragma unroll
            for (int ks = 0; ks < 8; ++ks) a[ks] = cvt8(&xr[ks * 32 + q * 8]);
        } else {
#pragma unroll
            for (int ks = 0; ks < 8; ++ks)
                a[ks] = *(const bf16x8*)&Xb[(row0 + n) * 256 + ks * 32 + q * 8];
        }
        f32x4 acc[16];
#pragma unroll
        for (int nt = 0; nt < 16; ++nt) acc[nt] = (f32x4){0.f, 0.f, 0.f, 0.f};
#pragma unroll
        for (int nt = 0; nt < 16; ++nt) {
#pragma unroll
            for (int ks = 0; ks < 8; ++ks) {
                bf16x8 bv = *(const bf16x8*)&Ws[(nt * 16 + n) * 256 +
                                                (((ks * 4 + q) ^ sw) * 8)];
                acc[nt] = __builtin_amdgcn_mfma_f32_16x16x32_bf16(a[ks], bv, acc[nt], 0, 0, 0);
            }
        }
        // epilogue: output row = row0 + q*4 + r, col = nt*16 + n.
        float mean4[4], inv4[4];
#pragma unroll
        for (int r = 0; r < 4; ++r) {
            float s = 0.f, sq = 0.f;
#pragma unroll
            for (int nt = 0; nt < 16; ++nt) {
                float h = acc[nt][r] + bcol[nt];
                h = h >= 0.f ? h : 0.01f * h;
                acc[nt][r] = h;
                s += h; sq += h * h;
            }
#pragma unroll
            for (int m = 1; m < 16; m <<= 1) {
                s += __shfl_xor(s, m, 64);
                sq += __shfl_xor(sq, m, 64);
            }
            float mean = s * (1.f / 256.f);
            float var = fmaxf(sq * (1.f / 256.f) - mean * mean, 0.f);
            mean4[r] = mean;
            inv4[r] = rsqrtf(var + 1e-5f);
        }
        float nr[4] = {0.f, 0.f, 0.f, 0.f};
#pragma unroll
        for (int nt = 0; nt < 16; ++nt) {
#pragma unroll
            for (int r = 0; r < 4; ++r) {
                float o = (acc[nt][r] - mean4[r]) * inv4[r] * gcol[nt] + ecol[nt];
                unsigned short ob = f2bf(o);
                float of = bf2f(ob);
                nr[r] += of * of;
                Yout[(row0 + q * 4 + r) * 256 + nt * 16 + n] = ob;
            }
        }
        if (norms) {
#pragma unroll
            for (int r = 0; r < 4; ++r) {
#pragma unroll
                for (int m = 1; m < 16; m <<= 1) nr[r] += __shfl_xor(nr[r], m, 64);
                if (n == 0) norms[row0 + q * 4 + r] = nr[r];
            }
        }
    }
}

// Panel cost kernel: block = (batch b, 64-row panel i0). 512 threads (8 waves).
// Stage A once; loop over 8 B column-tiles, double-buffered global_load_lds.
__global__ __launch_bounds__(512) void cost_mfma_kernel(
    const unsigned short* __restrict__ E, const float* __restrict__ norms,
    const int* __restrict__ argA, const int* __restrict__ argB,
    const float* __restrict__ pa, const float* __restrict__ pb,
    unsigned short* __restrict__ Kb16, float* __restrict__ acc,
    float* __restrict__ colsum) {
    __shared__ unsigned short As[64 * 256];       // 32 KB
    __shared__ unsigned short Bs[2][64 * 256];    // 64 KB
    __shared__ float cswave[8][256];              // 8 KB per-wave colsum partials
    __shared__ float redp[8];
    const int t = threadIdx.x;
    const int L = t & 63, wv = t >> 6;
    const int q = L >> 4, n = L & 15;
    const int rh = wv & 3, ch = wv >> 2;
    // b = id&63 so a batch's 8 panels share an XCD (id%8 == b%8)
    const int b = blockIdx.x & 63;
    const int i0 = (blockIdx.x >> 6) * 64;
    const unsigned short* eA = E + (size_t)b * 512 * 256;
    const unsigned short* eB = E + (size_t)(32768 + b * 512) * 256;
    const int lrow = L >> 5, segp = L & 31;

#pragma unroll
    for (int jj = 0; jj < 4; ++jj) {
        int row = wv * 8 + 2 * jj + lrow;
        int sseg = segp ^ (row & 7);
        __builtin_amdgcn_global_load_lds((as1cv)&eA[(size_t)(i0 + row) * 256 + sseg * 8],
                                         (as3v)&As[(wv * 8 + 2 * jj) * 256], 16, 0, 0);
        __builtin_amdgcn_global_load_lds((as1cv)&eB[(size_t)row * 256 + sseg * 8],
                                         (as3v)&Bs[0][(wv * 8 + 2 * jj) * 256], 16, 0, 0);
    }
    const int base_row = i0 + rh * 16 + q * 4;
    float nA[4], pAr[4]; int cA[4];
#pragma unroll
    for (int rr = 0; rr < 4; ++rr) {
        nA[rr] = norms[b * 512 + base_row + rr];
        pAr[rr] = pa[b * 512 + base_row + rr];
        cA[rr] = argA[b * 512 + base_row + rr];
    }
    float part = 0.f;
    __syncthreads();   // A + B0 staged

    const int rowa = rh * 16 + n;
    const int sw = n & 7;
    bf16x8 areg[8];
#pragma unroll
    for (int c = 0; c < 8; ++c)
        areg[c] = *(const bf16x8*)&As[rowa * 256 + (((c * 4 + q) ^ sw) * 8)];

    for (int j = 0; j < 8; ++j) {
        const int cur = j & 1;
        if (j < 7) {
#pragma unroll
            for (int jj = 0; jj < 4; ++jj) {
                int row = wv * 8 + 2 * jj + lrow;
                int sseg = segp ^ (row & 7);
                __builtin_amdgcn_global_load_lds(
                    (as1cv)&eB[(size_t)((j + 1) * 64 + row) * 256 + sseg * 8],
                    (as3v)&Bs[cur ^ 1][(wv * 8 + 2 * jj) * 256], 16, 0, 0);
            }
        }
        f32x4 dot[2];
        dot[0] = (f32x4){0.f, 0.f, 0.f, 0.f};
        dot[1] = (f32x4){0.f, 0.f, 0.f, 0.f};
#pragma unroll
        for (int c = 0; c < 8; ++c) {
#pragma unroll
            for (int np = 0; np < 2; ++np) {
                int nt = ch * 2 + np;
                bf16x8 bv = *(const bf16x8*)&Bs[cur][(nt * 16 + n) * 256 +
                                                     (((c * 4 + q) ^ sw) * 8)];
                dot[np] = __builtin_amdgcn_mfma_f32_16x16x32_bf16(areg[c], bv, dot[np], 0, 0, 0);
            }
        }
#pragma unroll
        for (int np = 0; np < 2; ++np) {
            int nt = ch * 2 + np;
            int col = j * 64 + nt * 16 + n;
            float nB = norms[32768 + b * 512 + col];
            float pB = pb[b * 512 + col];
            int cB = argB[b * 512 + col];
            float cloc = 0.f;
#pragma unroll
            for (int rr = 0; rr < 4; ++rr) {
                float d2 = nA[rr] + nB - 2.f * dot[np][rr];
                float c = sqrtf(fmaxf(d2, 0.f));
                float pm = pAr[rr] * pB;
                float cc = c + (BIGF - BIGF * pm);
                float sgn = (cA[rr] == cB) ? 1.f : -1.f;
                part += cc * sgn * pm;
                unsigned short kb = f2bf(expf(-2.f * cc));
                Kb16[((size_t)b * 512 + base_row + rr) * 512 + col] = kb;
                cloc += bf2f(kb);
            }
            cloc += __shfl_xor(cloc, 16, 64);
            cloc += __shfl_xor(cloc, 32, 64);
            if (L < 16) cswave[wv][j * 32 + np * 16 + L] = cloc;
        }
        __syncthreads();
    }

    {
        float pw = part;
#pragma unroll
        for (int off = 32; off > 0; off >>= 1) pw += __shfl_down(pw, off, 64);
        if (L == 0) redp[wv] = pw;
    }
    __syncthreads();
    {
        int c = t & 511;
        int local = ((c >> 6) << 5) | (c & 31);
        int cch = (c >> 5) & 1;
        float s = cswave[4 * cch][local] + cswave[4 * cch + 1][local] +
                  cswave[4 * cch + 2][local] + cswave[4 * cch + 3][local];
        atomicAdd(&colsum[(size_t)b * 512 + c], s);
    }
    if (t == 0) {
        float s = 0.f;
#pragma unroll
        for (int k = 0; k < 8; ++k) s += redp[k];
        atomicAdd(&acc[ACC_IN + b], s);
    }
}

// Fused Sinkhorn: 9 fused passes (pass-0 folded into cost via colsum;
// final u-pass folded into sup). Writes v only.
__global__ __launch_bounds__(1024) void sinkhorn_kernel(
    const unsigned short* __restrict__ Kb16, const float* __restrict__ colsum,
    float* __restrict__ v) {
    const int b = blockIdx.x;
    const unsigned short* Kb = Kb16 + (size_t)b * 262144;
    __shared__ float vv[512];
    __shared__ float cp[16][512];
    const int t = threadIdx.x, wv = t >> 6, l = t & 63;
    const unsigned short* base = Kb + (size_t)(wv * 32) * 512 + l * 8;

    if (t < 512) vv[t] = 1.f / colsum[(size_t)b * 512 + t];
    __syncthreads();

    for (int it = 1; it <= 9; ++it) {
        float vr[8];
        *(f32x4*)&vr[0] = *(const f32x4*)&vv[l * 8];
        *(f32x4*)&vr[4] = *(const f32x4*)&vv[l * 8 + 4];
        float cs[8];
#pragma unroll
        for (int e = 0; e < 8; ++e) cs[e] = 0.f;
#pragma unroll 2
        for (int g = 0; g < 8; ++g) {
            const unsigned short* gb = base + (size_t)(g * 4) * 512;
            uint4 w0 = *(const uint4*)(gb);
            uint4 w1 = *(const uint4*)(gb + 512);
            uint4 w2 = *(const uint4*)(gb + 1024);
            uint4 w3 = *(const uint4*)(gb + 1536);
            float k0[8], k1[8], k2[8], k3[8];
            unpack8(w0, k0); unpack8(w1, k1); unpack8(w2, k2); unpack8(w3, k3);
            float p0 = dot8(k0, vr);
            float p1 = dot8(k1, vr);
            float p2 = dot8(k2, vr);
            float p3 = dot8(k3, vr);
            float s = packed_reduce4(p0, p1, p2, p3, l);
            float us = 0.001953125f * __builtin_amdgcn_rcpf(s);
            float uA = bcast_lane(us, 0);
            float uC = bcast_lane(us, 16);
            float uB = bcast_lane(us, 32);
            float uD = bcast_lane(us, 48);
#pragma unroll
            for (int e = 0; e < 8; ++e) {
                float c = fmaf(k0[e], uA, cs[e]);
                c = fmaf(k1[e], uB, c);
                c = fmaf(k2[e], uC, c);
                cs[e] = fmaf(k3[e], uD, c);
            }
        }
        *(f32x4*)&cp[wv][l * 8]     = *(f32x4*)&cs[0];
        *(f32x4*)&cp[wv][l * 8 + 4] = *(f32x4*)&cs[4];
        __syncthreads();
        if (t < 512) {
            float ss = 0.f;
#pragma unroll
            for (int k = 0; k < 16; ++k) ss += cp[k][t];
            vv[t] = (1.f / 512.f) / ss;
        }
        __syncthreads();
    }
    if (t < 512) v[(size_t)b * 512 + t] = vv[t];
}

// sup loss; computes u_i on the fly: u_i*512 = 1/(K@v)_i.
__global__ __launch_bounds__(256) void sup_kernel(
    const unsigned short* __restrict__ Kb16, const float* __restrict__ v,
    const float* __restrict__ rel, const float* __restrict__ pa,
    float* __restrict__ acc) {
    const int b = blockIdx.x >> 6;
    const int rg = blockIdx.x & 63;
    const int t = threadIdx.x;
    const int h = t >> 5;
    const int c = t & 31;
    const int row = rg * 8 + h;
    const unsigned int* kp =
        (const unsigned int*)(Kb16 + ((size_t)b * 512 + row) * 512 + c * 16);
    uint4 kw0 = *(const uint4*)(kp);
    uint4 kw1 = *(const uint4*)(kp + 4);
    float k[16];
    unpack8(kw0, k); unpack8(kw1, k + 8);
    float vr[16];
    *(f32x4*)&vr[0]  = *(const f32x4*)&v[b * 512 + c * 16];
    *(f32x4*)&vr[4]  = *(const f32x4*)&v[b * 512 + c * 16 + 4];
    *(f32x4*)&vr[8]  = *(const f32x4*)&v[b * 512 + c * 16 + 8];
    *(f32x4*)&vr[12] = *(const f32x4*)&v[b * 512 + c * 16 + 12];
    float rs = 0.f;
#pragma unroll
    for (int e = 0; e < 16; ++e) rs = fmaf(k[e], vr[e], rs);
#pragma unroll
    for (int off = 16; off > 0; off >>= 1) rs += __shfl_xor(rs, off, 32);
    float inv = 1.f / rs;
    float part = 0.f;
    const float* rp = &rel[((size_t)b * 512 + row) * 512 + c * 16];
#pragma unroll
    for (int e = 0; e < 16; e += 4) {
        float4 r4 = *(const float4*)(rp + e);
        float d0 = k[e]     * vr[e]     * inv - r4.x;
        float d1 = k[e + 1] * vr[e + 1] * inv - r4.y;
        float d2 = k[e + 2] * vr[e + 2] * inv - r4.z;
        float d3 = k[e + 3] * vr[e + 3] * inv - r4.w;
        part += d0 * d0 + d1 * d1 + d2 * d2 + d3 * d3;
    }
    part *= pa[b * 512 + row];
    float tot = block_reduce_256(part);
    if (t == 0) atomicAdd(&acc[ACC_SUP + (blockIdx.x & 255)], tot);
}

__global__ __launch_bounds__(256) void final_kernel(const float* __restrict__ acc,
                                                    float* __restrict__ out) {
    int t = threadIdx.x;
    float vin = (t < 64) ? acc[ACC_IN + t] : 0.f;
    float sIn = block_reduce_256(vin);
    float vsup = acc[ACC_SUP + t];
    float sSup = block_reduce_256(vsup);
    if (t == 0)
        out[0] = sIn * (1.f / 16777216.f) + 10.f * sSup / acc[ACC_PA];
}

extern "C" void kernel_launch(void* const* d_in, const int* in_sizes, int n_in,
                              void* d_out, int out_size, void* d_ws, size_t ws_size,
                              hipStream_t stream) {
    const float* la  = (const float*)d_in[0];
    const float* lb  = (const float*)d_in[1];
    const float* xA  = (const float*)d_in[2];
    const float* xB  = (const float*)d_in[3];
    const float* rel = (const float*)d_in[4];
    const float* pa  = (const float*)d_in[5];
    const float* pb  = (const float*)d_in[6];
    const float* W1  = (const float*)d_in[7];
    const float* b1  = (const float*)d_in[8];
    const float* g1  = (const float*)d_in[9];
    const float* be1 = (const float*)d_in[10];
    const float* W2  = (const float*)d_in[11];
    const float* b2  = (const float*)d_in[12];
    const float* g2  = (const float*)d_in[13];
    const float* be2 = (const float*)d_in[14];
    float* out = (float*)d_out;

    float* ws = (float*)d_ws;
    unsigned short* Kb16 = (unsigned short*)(ws + KB_OFF);
    unsigned short* Ebf  = (unsigned short*)(ws + X_OFF);    // layer-2 output
    unsigned short* Hbf  = (unsigned short*)(ws + H_OFF);
    float* norms = ws + NORM_OFF;
    float* u     = ws + U_OFF;    // colsum staging
    float* v     = ws + V_OFF;
    int* argA    = (int*)(ws + ARGA_OFF);
    int* argB    = (int*)(ws + ARGB_OFF);
    float* acc   = ws + ACC_OFF;
    unsigned short* Wt1 = (unsigned short*)(ws + WT1_OFF);
    unsigned short* Wt2 = (unsigned short*)(ws + WT2_OFF);

    zero_acc_kernel<<<128, 256, 0, stream>>>(acc, u);        // zero acc + colsum
    argmax_pa_kernel<<<128, 256, 0, stream>>>(la, lb, pa, argA, argB, acc);

    // weight transpose-casts (tiny)
    cast_wt_kernel<<<dim3(16, 16), 256, 0, stream>>>(W1, Wt1);
    cast_wt_kernel<<<dim3(16, 16), 256, 0, stream>>>(W2, Wt2);

    // fused layer 1 (f32 input, in-register cast) and layer 2 (bf16 input)
    gemmln_kernel<<<256, 512, 0, stream>>>(xA, xB, nullptr, Wt1, b1, g1, be1, Hbf, nullptr);
    gemmln_kernel<<<256, 512, 0, stream>>>(nullptr, nullptr, Hbf, Wt2, b2, g2, be2, Ebf, norms);

    // cost + K (bf16) + column sums: 512 panel blocks x 512 threads
    cost_mfma_kernel<<<512, 512, 0, stream>>>(Ebf, norms, argA, argB, pa, pb,
                                              Kb16, acc, u);

    // sinkhorn: 9 fused K-passes (pass-0 in cost, final u-pass in sup)
    sinkhorn_kernel<<<64, 1024, 0, stream>>>(Kb16, u, v);

    sup_kernel<<<4096, 256, 0, stream>>>(Kb16, v, rel, pa, acc);
    final_kernel<<<1, 256, 0, stream>>>(acc, out);
}

// Round 13
// 326.041 us; speedup vs baseline: 1.2889x; 1.0289x over previous
//
#include <hip/hip_runtime.h>
#include <math.h>

// Problem constants
#define BSZ 64
#define NPTS 512
#define DIM 256
#define MROWS 32768      // BSZ*NPTS
#define TOTROWS 65536
#define BIGF 1.0e9f

typedef __bf16 bf16x8 __attribute__((ext_vector_type(8)));
typedef float  f32x4  __attribute__((ext_vector_type(4)));
typedef __attribute__((address_space(1))) const void* as1cv;
typedef __attribute__((address_space(3))) void* as3v;

// ws layout (float offsets)
#define KB_OFF    0ull          // ushort[16777216]: K(bf16)
#define X_OFF     8388608ull    // ushort[16777216]: Ebf (layer-2 output)
#define H_OFF     16777216ull   // ushort[16777216]: Hbf
#define NORM_OFF  25165824ull   // 65536 f32
#define U_OFF     25231360ull   // 32768 f32 (colsum staged here pre-sinkhorn)
#define V_OFF     25264128ull   // 32768 f32
#define ARGA_OFF  25296896ull   // 32768 int
#define ARGB_OFF  25329664ull   // 32768 int
#define ACC_OFF   25362432ull   // 512 f32
#define WT1_OFF   25362944ull   // ushort[65536]
#define WT2_OFF   25395712ull   // ushort[65536]

#define ACC_PA   0
#define ACC_IN   1     // 64 slots
#define ACC_SUP  65    // 256 slots
#define ACC_CNT  321

__device__ __forceinline__ float bf2f(unsigned short h) {
    return __uint_as_float(((unsigned int)h) << 16);
}
__device__ __forceinline__ unsigned short f2bf(float f) {
    unsigned int u = __float_as_uint(f);
    u = (u + 0x7FFFu + ((u >> 16) & 1u)) >> 16;
    return (unsigned short)u;
}

// convert 8 consecutive f32 -> bf16x8 fragment (same f2bf RNE as the old cast)
__device__ __forceinline__ bf16x8 cvt8(const float* p) {
    float4 f0 = *(const float4*)p;
    float4 f1 = *(const float4*)(p + 4);
    union { unsigned short s[8]; bf16x8 v; } r;
    r.s[0] = f2bf(f0.x); r.s[1] = f2bf(f0.y); r.s[2] = f2bf(f0.z); r.s[3] = f2bf(f0.w);
    r.s[4] = f2bf(f1.x); r.s[5] = f2bf(f1.y); r.s[6] = f2bf(f1.z); r.s[7] = f2bf(f1.w);
    return r.v;
}

// re-entrant, 256-thread blocks only
__device__ __forceinline__ float block_reduce_256(float val) {
    __shared__ float sh[4];
    int lane = threadIdx.x & 63;
    int wv = threadIdx.x >> 6;
    __syncthreads();
#pragma unroll
    for (int off = 32; off > 0; off >>= 1) val += __shfl_down(val, off, 64);
    if (lane == 0) sh[wv] = val;
    __syncthreads();
    float r = 0.f;
    if (wv == 0 && lane < 4) r = sh[lane];
    if (wv == 0) {
        r += __shfl_down(r, 2, 64);
        r += __shfl_down(r, 1, 64);
    }
    return r;  // valid in thread 0
}

__device__ __forceinline__ void unpack8(uint4 w, float* k) {
    k[0] = __uint_as_float(w.x << 16);
    k[1] = __uint_as_float(w.x & 0xFFFF0000u);
    k[2] = __uint_as_float(w.y << 16);
    k[3] = __uint_as_float(w.y & 0xFFFF0000u);
    k[4] = __uint_as_float(w.z << 16);
    k[5] = __uint_as_float(w.z & 0xFFFF0000u);
    k[6] = __uint_as_float(w.w << 16);
    k[7] = __uint_as_float(w.w & 0xFFFF0000u);
}
__device__ __forceinline__ float dot8(const float* k, const float* vr) {
    float rs = k[0] * vr[0];
    rs = fmaf(k[1], vr[1], rs); rs = fmaf(k[2], vr[2], rs);
    rs = fmaf(k[3], vr[3], rs); rs = fmaf(k[4], vr[4], rs);
    rs = fmaf(k[5], vr[5], rs); rs = fmaf(k[6], vr[6], rs);
    return fmaf(k[7], vr[7], rs);
}

// Packed 4-row all-lanes reduce: rows A,B,C,D per-lane partials -> row sums,
// replicated within 16-lane groups: g0=A, g1=C, g2=B, g3=D. 10 DS ops for 4 rows.
__device__ __forceinline__ float packed_reduce4(float p0, float p1, float p2, float p3, int l) {
    p0 += __shfl_xor(p0, 32, 64);
    p1 += __shfl_xor(p1, 32, 64);
    p2 += __shfl_xor(p2, 32, 64);
    p3 += __shfl_xor(p3, 32, 64);
    float m1 = (l & 32) ? p1 : p0;
    float m2 = (l & 32) ? p3 : p2;
    m1 += __shfl_xor(m1, 16, 64);
    m2 += __shfl_xor(m2, 16, 64);
    float s = (l & 16) ? m2 : m1;
    s += __shfl_xor(s, 8, 64);
    s += __shfl_xor(s, 4, 64);
    s += __shfl_xor(s, 2, 64);
    s += __shfl_xor(s, 1, 64);
    return s;
}
__device__ __forceinline__ float bcast_lane(float x, int lane) {
    return __uint_as_float((unsigned)__builtin_amdgcn_readlane((int)__float_as_uint(x), lane));
}

__global__ void zero_acc_kernel(float* acc, float* colsum) {
    int t = blockIdx.x * 256 + threadIdx.x;   // grid 128*256 = 32768
    if (t < 512) acc[t] = 0.f;
    colsum[t] = 0.f;
}

__global__ __launch_bounds__(256) void argmax_pa_kernel(
    const float* __restrict__ la, const float* __restrict__ lb,
    const float* __restrict__ pa, int* __restrict__ argA, int* __restrict__ argB,
    float* __restrict__ acc) {
    int i = blockIdx.x * 256 + threadIdx.x;
    float4 a = *(const float4*)&la[(size_t)i * 4];
    float av[4] = {a.x, a.y, a.z, a.w};
    int ba = 0; float bv = av[0];
#pragma unroll
    for (int c = 1; c < 4; ++c) if (av[c] > bv) { bv = av[c]; ba = c; }
    argA[i] = ba;
    float4 b = *(const float4*)&lb[(size_t)i * 4];
    float bw[4] = {b.x, b.y, b.z, b.w};
    int bbi = 0; float bm = bw[0];
#pragma unroll
    for (int c = 1; c < 4; ++c) if (bw[c] > bm) { bm = bw[c]; bbi = c; }
    argB[i] = bbi;
    float p = pa[i];
#pragma unroll
    for (int off = 32; off > 0; off >>= 1) p += __shfl_down(p, off, 64);
    if ((threadIdx.x & 63) == 0) atomicAdd(&acc[ACC_PA], p);
}

// W[256][256] f32 -> Wt[n][k] bf16 (transposed)
__global__ __launch_bounds__(256) void cast_wt_kernel(
    const float* __restrict__ W, unsigned short* __restrict__ Wt) {
    __shared__ float tile[16][17];
    int tx = threadIdx.x & 15, ty = threadIdx.x >> 4;
    int bx = blockIdx.x, by = blockIdx.y;
    tile[ty][tx] = W[(size_t)(by * 16 + ty) * 256 + bx * 16 + tx];
    __syncthreads();
    Wt[(size_t)(bx * 16 + ty) * 256 + by * 16 + tx] = f2bf(tile[tx][ty]);
}

// Fused GEMM + bias + leaky + LayerNorm. One persistent block per 256 rows:
// Wt (256x256 bf16 = 128KB) staged ONCE via global_load_lds (seg XOR swizzle);
// A fragments loaded straight global->VGPR. Layer 1 (XfA/XfB non-null) reads
// the f32 inputs directly and converts in-register (identical f2bf RNE).
// Layer 2 reads bf16 Hbf. LN applied in-register on the f32 accumulator.
// 256 blocks x 512 threads (8 waves, 2/SIMD). 2 panel-iterations of 128 rows.
__global__ __launch_bounds__(512) void gemmln_kernel(
    const float* __restrict__ XfA, const float* __restrict__ XfB,
    const unsigned short* __restrict__ Xb,
    const unsigned short* __restrict__ Wt,
    const float* __restrict__ bias, const float* __restrict__ gam,
    const float* __restrict__ bet,
    unsigned short* __restrict__ Yout, float* __restrict__ norms) {
    __shared__ unsigned short Ws[256 * 256];   // 128 KB, row = n, 512B, swizzled
    const int t = threadIdx.x;
    const int L = t & 63, wv = t >> 6;
    const int q = L >> 4, n = L & 15;
    {
        const int lrow = L >> 5, segp = L & 31;
#pragma unroll
        for (int j = 0; j < 16; ++j) {
            int row = wv * 32 + 2 * j + lrow;
            int sseg = segp ^ (row & 7);
            __builtin_amdgcn_global_load_lds((as1cv)&Wt[(size_t)row * 256 + sseg * 8],
                                             (as3v)&Ws[(wv * 32 + 2 * j) * 256], 16, 0, 0);
        }
    }
    float bcol[16], gcol[16], ecol[16];
#pragma unroll
    for (int nt = 0; nt < 16; ++nt) {
        bcol[nt] = bias[nt * 16 + n];
        gcol[nt] = gam[nt * 16 + n];
        ecol[nt] = bet[nt * 16 + n];
    }
    __syncthreads();   // Wt staged

    const int sw = n & 7;
    for (int p = 0; p < 2; ++p) {
        const size_t row0 = (size_t)blockIdx.x * 256 + p * 128 + wv * 16;
        bf16x8 a[8];
        if (XfA) {
            const float* Xf = (blockIdx.x < 128) ? XfA : XfB;
            const size_t lrow = ((size_t)(blockIdx.x & 127)) * 256 + p * 128 + wv * 16 + n;
            const float* xr = &Xf[lrow * 256];
#pragma unroll
            for (int ks = 0; ks < 8; ++ks) a[ks] = cvt8(&xr[ks * 32 + q * 8]);
        } else {
#pragma unroll
            for (int ks = 0; ks < 8; ++ks)
                a[ks] = *(const bf16x8*)&Xb[(row0 + n) * 256 + ks * 32 + q * 8];
        }
        f32x4 acc[16];
#pragma unroll
        for (int nt = 0; nt < 16; ++nt) acc[nt] = (f32x4){0.f, 0.f, 0.f, 0.f};
#pragma unroll
        for (int nt = 0; nt < 16; ++nt) {
#pragma unroll
            for (int ks = 0; ks < 8; ++ks) {
                bf16x8 bv = *(const bf16x8*)&Ws[(nt * 16 + n) * 256 +
                                                (((ks * 4 + q) ^ sw) * 8)];
                acc[nt] = __builtin_amdgcn_mfma_f32_16x16x32_bf16(a[ks], bv, acc[nt], 0, 0, 0);
            }
        }
        float mean4[4], inv4[4];
#pragma unroll
        for (int r = 0; r < 4; ++r) {
            float s = 0.f, sq = 0.f;
#pragma unroll
            for (int nt = 0; nt < 16; ++nt) {
                float h = acc[nt][r] + bcol[nt];
                h = h >= 0.f ? h : 0.01f * h;
                acc[nt][r] = h;
                s += h; sq += h * h;
            }
#pragma unroll
            for (int m = 1; m < 16; m <<= 1) {
                s += __shfl_xor(s, m, 64);
                sq += __shfl_xor(sq, m, 64);
            }
            float mean = s * (1.f / 256.f);
            float var = fmaxf(sq * (1.f / 256.f) - mean * mean, 0.f);
            mean4[r] = mean;
            inv4[r] = rsqrtf(var + 1e-5f);
        }
        float nr[4] = {0.f, 0.f, 0.f, 0.f};
#pragma unroll
        for (int nt = 0; nt < 16; ++nt) {
#pragma unroll
            for (int r = 0; r < 4; ++r) {
                float o = (acc[nt][r] - mean4[r]) * inv4[r] * gcol[nt] + ecol[nt];
                unsigned short ob = f2bf(o);
                float of = bf2f(ob);
                nr[r] += of * of;
                Yout[(row0 + q * 4 + r) * 256 + nt * 16 + n] = ob;
            }
        }
        if (norms) {
#pragma unroll
            for (int r = 0; r < 4; ++r) {
#pragma unroll
                for (int m = 1; m < 16; m <<= 1) nr[r] += __shfl_xor(nr[r], m, 64);
                if (n == 0) norms[row0 + q * 4 + r] = nr[r];
            }
        }
    }
}

// Panel cost kernel: block = (batch b, 64-row panel i0). 512 threads (8 waves).
// LDS cut to 72 KB -> 2 blocks/CU (4 waves/SIMD): A staged through Bs[0],
// extracted to registers, then the same double-buffered B pipeline. Cross-block
// TLP covers the per-tile staging drain that 1-block/CU couldn't hide.
__global__ __launch_bounds__(512, 4) void cost_mfma_kernel(
    const unsigned short* __restrict__ E, const float* __restrict__ norms,
    const int* __restrict__ argA, const int* __restrict__ argB,
    const float* __restrict__ pa, const float* __restrict__ pb,
    unsigned short* __restrict__ Kb16, float* __restrict__ acc,
    float* __restrict__ colsum) {
    __shared__ unsigned short Bs[2][64 * 256];    // 64 KB (Bs[0] stages A first)
    __shared__ float cswave[8][256];              // 8 KB per-wave colsum partials
    __shared__ float redp[8];
    const int t = threadIdx.x;
    const int L = t & 63, wv = t >> 6;
    const int q = L >> 4, n = L & 15;
    const int rh = wv & 3, ch = wv >> 2;
    // b = id&63 so a batch's 8 panels share an XCD (id%8 == b%8)
    const int b = blockIdx.x & 63;
    const int i0 = (blockIdx.x >> 6) * 64;
    const unsigned short* eA = E + (size_t)b * 512 * 256;
    const unsigned short* eB = E + (size_t)(32768 + b * 512) * 256;
    const int lrow = L >> 5, segp = L & 31;

    // stage A panel into Bs[0]
#pragma unroll
    for (int jj = 0; jj < 4; ++jj) {
        int row = wv * 8 + 2 * jj + lrow;
        int sseg = segp ^ (row & 7);
        __builtin_amdgcn_global_load_lds((as1cv)&eA[(size_t)(i0 + row) * 256 + sseg * 8],
                                         (as3v)&Bs[0][(wv * 8 + 2 * jj) * 256], 16, 0, 0);
    }
    const int base_row = i0 + rh * 16 + q * 4;
    float nA[4], pAr[4]; int cA[4];
#pragma unroll
    for (int rr = 0; rr < 4; ++rr) {
        nA[rr] = norms[b * 512 + base_row + rr];
        pAr[rr] = pa[b * 512 + base_row + rr];
        cA[rr] = argA[b * 512 + base_row + rr];
    }
    float part = 0.f;
    __syncthreads();   // A staged

    // extract A fragments to registers, then free Bs[0]
    const int rowa = rh * 16 + n;
    const int sw = n & 7;
    bf16x8 areg[8];
#pragma unroll
    for (int c = 0; c < 8; ++c)
        areg[c] = *(const bf16x8*)&Bs[0][rowa * 256 + (((c * 4 + q) ^ sw) * 8)];
    __syncthreads();   // all extractions complete; Bs[0] reusable

    // stage B tile 0 into Bs[1]
#pragma unroll
    for (int jj = 0; jj < 4; ++jj) {
        int row = wv * 8 + 2 * jj + lrow;
        int sseg = segp ^ (row & 7);
        __builtin_amdgcn_global_load_lds((as1cv)&eB[(size_t)row * 256 + sseg * 8],
                                         (as3v)&Bs[1][(wv * 8 + 2 * jj) * 256], 16, 0, 0);
    }
    __syncthreads();   // B0 ready (in Bs[1])

    for (int j = 0; j < 8; ++j) {
        const int cur = (j + 1) & 1;          // j=0 -> Bs[1], j=1 -> Bs[0], ...
        if (j < 7) {                          // prefetch B(j+1) into freed buffer
#pragma unroll
            for (int jj = 0; jj < 4; ++jj) {
                int row = wv * 8 + 2 * jj + lrow;
                int sseg = segp ^ (row & 7);
                __builtin_amdgcn_global_load_lds(
                    (as1cv)&eB[(size_t)((j + 1) * 64 + row) * 256 + sseg * 8],
                    (as3v)&Bs[j & 1][(wv * 8 + 2 * jj) * 256], 16, 0, 0);
            }
        }
        f32x4 dot[2];
        dot[0] = (f32x4){0.f, 0.f, 0.f, 0.f};
        dot[1] = (f32x4){0.f, 0.f, 0.f, 0.f};
#pragma unroll
        for (int c = 0; c < 8; ++c) {
#pragma unroll
            for (int np = 0; np < 2; ++np) {
                int nt = ch * 2 + np;
                bf16x8 bv = *(const bf16x8*)&Bs[cur][(nt * 16 + n) * 256 +
                                                     (((c * 4 + q) ^ sw) * 8)];
                dot[np] = __builtin_amdgcn_mfma_f32_16x16x32_bf16(areg[c], bv, dot[np], 0, 0, 0);
            }
        }
#pragma unroll
        for (int np = 0; np < 2; ++np) {
            int nt = ch * 2 + np;
            int col = j * 64 + nt * 16 + n;
            float nB = norms[32768 + b * 512 + col];
            float pB = pb[b * 512 + col];
            int cB = argB[b * 512 + col];
            float cloc = 0.f;
#pragma unroll
            for (int rr = 0; rr < 4; ++rr) {
                float d2 = nA[rr] + nB - 2.f * dot[np][rr];
                float c = sqrtf(fmaxf(d2, 0.f));
                float pm = pAr[rr] * pB;
                float cc = c + (BIGF - BIGF * pm);
                float sgn = (cA[rr] == cB) ? 1.f : -1.f;
                part += cc * sgn * pm;
                unsigned short kb = f2bf(expf(-2.f * cc));
                Kb16[((size_t)b * 512 + base_row + rr) * 512 + col] = kb;
                cloc += bf2f(kb);
            }
            cloc += __shfl_xor(cloc, 16, 64);
            cloc += __shfl_xor(cloc, 32, 64);
            if (L < 16) cswave[wv][j * 32 + np * 16 + L] = cloc;
        }
        __syncthreads();   // drains prefetch + retires Bs[cur] reads
    }

    {
        float pw = part;
#pragma unroll
        for (int off = 32; off > 0; off >>= 1) pw += __shfl_down(pw, off, 64);
        if (L == 0) redp[wv] = pw;
    }
    __syncthreads();
    {
        int c = t & 511;
        int local = ((c >> 6) << 5) | (c & 31);
        int cch = (c >> 5) & 1;
        float s = cswave[4 * cch][local] + cswave[4 * cch + 1][local] +
                  cswave[4 * cch + 2][local] + cswave[4 * cch + 3][local];
        atomicAdd(&colsum[(size_t)b * 512 + c], s);
    }
    if (t == 0) {
        float s = 0.f;
#pragma unroll
        for (int k = 0; k < 8; ++k) s += redp[k];
        atomicAdd(&acc[ACC_IN + b], s);
    }
}

// Fused Sinkhorn: 9 fused passes (pass-0 folded into cost via colsum;
// final u-pass folded into sup). Writes v only.
__global__ __launch_bounds__(1024) void sinkhorn_kernel(
    const unsigned short* __restrict__ Kb16, const float* __restrict__ colsum,
    float* __restrict__ v) {
    const int b = blockIdx.x;
    const unsigned short* Kb = Kb16 + (size_t)b * 262144;
    __shared__ float vv[512];
    __shared__ float cp[16][512];
    const int t = threadIdx.x, wv = t >> 6, l = t & 63;
    const unsigned short* base = Kb + (size_t)(wv * 32) * 512 + l * 8;

    if (t < 512) vv[t] = 1.f / colsum[(size_t)b * 512 + t];
    __syncthreads();

    for (int it = 1; it <= 9; ++it) {
        float vr[8];
        *(f32x4*)&vr[0] = *(const f32x4*)&vv[l * 8];
        *(f32x4*)&vr[4] = *(const f32x4*)&vv[l * 8 + 4];
        float cs[8];
#pragma unroll
        for (int e = 0; e < 8; ++e) cs[e] = 0.f;
#pragma unroll 2
        for (int g = 0; g < 8; ++g) {
            const unsigned short* gb = base + (size_t)(g * 4) * 512;
            uint4 w0 = *(const uint4*)(gb);
            uint4 w1 = *(const uint4*)(gb + 512);
            uint4 w2 = *(const uint4*)(gb + 1024);
            uint4 w3 = *(const uint4*)(gb + 1536);
            float k0[8], k1[8], k2[8], k3[8];
            unpack8(w0, k0); unpack8(w1, k1); unpack8(w2, k2); unpack8(w3, k3);
            float p0 = dot8(k0, vr);
            float p1 = dot8(k1, vr);
            float p2 = dot8(k2, vr);
            float p3 = dot8(k3, vr);
            float s = packed_reduce4(p0, p1, p2, p3, l);
            float us = 0.001953125f * __builtin_amdgcn_rcpf(s);
            float uA = bcast_lane(us, 0);
            float uC = bcast_lane(us, 16);
            float uB = bcast_lane(us, 32);
            float uD = bcast_lane(us, 48);
#pragma unroll
            for (int e = 0; e < 8; ++e) {
                float c = fmaf(k0[e], uA, cs[e]);
                c = fmaf(k1[e], uB, c);
                c = fmaf(k2[e], uC, c);
                cs[e] = fmaf(k3[e], uD, c);
            }
        }
        *(f32x4*)&cp[wv][l * 8]     = *(f32x4*)&cs[0];
        *(f32x4*)&cp[wv][l * 8 + 4] = *(f32x4*)&cs[4];
        __syncthreads();
        if (t < 512) {
            float ss = 0.f;
#pragma unroll
            for (int k = 0; k < 16; ++k) ss += cp[k][t];
            vv[t] = (1.f / 512.f) / ss;
        }
        __syncthreads();
    }
    if (t < 512) v[(size_t)b * 512 + t] = vv[t];
}

// sup loss; computes u_i on the fly: u_i*512 = 1/(K@v)_i.
__global__ __launch_bounds__(256) void sup_kernel(
    const unsigned short* __restrict__ Kb16, const float* __restrict__ v,
    const float* __restrict__ rel, const float* __restrict__ pa,
    float* __restrict__ acc) {
    const int b = blockIdx.x >> 6;
    const int rg = blockIdx.x & 63;
    const int t = threadIdx.x;
    const int h = t >> 5;
    const int c = t & 31;
    const int row = rg * 8 + h;
    const unsigned int* kp =
        (const unsigned int*)(Kb16 + ((size_t)b * 512 + row) * 512 + c * 16);
    uint4 kw0 = *(const uint4*)(kp);
    uint4 kw1 = *(const uint4*)(kp + 4);
    float k[16];
    unpack8(kw0, k); unpack8(kw1, k + 8);
    float vr[16];
    *(f32x4*)&vr[0]  = *(const f32x4*)&v[b * 512 + c * 16];
    *(f32x4*)&vr[4]  = *(const f32x4*)&v[b * 512 + c * 16 + 4];
    *(f32x4*)&vr[8]  = *(const f32x4*)&v[b * 512 + c * 16 + 8];
    *(f32x4*)&vr[12] = *(const f32x4*)&v[b * 512 + c * 16 + 12];
    float rs = 0.f;
#pragma unroll
    for (int e = 0; e < 16; ++e) rs = fmaf(k[e], vr[e], rs);
#pragma unroll
    for (int off = 16; off > 0; off >>= 1) rs += __shfl_xor(rs, off, 32);
    float inv = 1.f / rs;
    float part = 0.f;
    const float* rp = &rel[((size_t)b * 512 + row) * 512 + c * 16];
#pragma unroll
    for (int e = 0; e < 16; e += 4) {
        float4 r4 = *(const float4*)(rp + e);
        float d0 = k[e]     * vr[e]     * inv - r4.x;
        float d1 = k[e + 1] * vr[e + 1] * inv - r4.y;
        float d2 = k[e + 2] * vr[e + 2] * inv - r4.z;
        float d3 = k[e + 3] * vr[e + 3] * inv - r4.w;
        part += d0 * d0 + d1 * d1 + d2 * d2 + d3 * d3;
    }
    part *= pa[b * 512 + row];
    float tot = block_reduce_256(part);
    if (t == 0) atomicAdd(&acc[ACC_SUP + (blockIdx.x & 255)], tot);
}

__global__ __launch_bounds__(256) void final_kernel(const float* __restrict__ acc,
                                                    float* __restrict__ out) {
    int t = threadIdx.x;
    float vin = (t < 64) ? acc[ACC_IN + t] : 0.f;
    float sIn = block_reduce_256(vin);
    float vsup = acc[ACC_SUP + t];
    float sSup = block_reduce_256(vsup);
    if (t == 0)
        out[0] = sIn * (1.f / 16777216.f) + 10.f * sSup / acc[ACC_PA];
}

extern "C" void kernel_launch(void* const* d_in, const int* in_sizes, int n_in,
                              void* d_out, int out_size, void* d_ws, size_t ws_size,
                              hipStream_t stream) {
    const float* la  = (const float*)d_in[0];
    const float* lb  = (const float*)d_in[1];
    const float* xA  = (const float*)d_in[2];
    const float* xB  = (const float*)d_in[3];
    const float* rel = (const float*)d_in[4];
    const float* pa  = (const float*)d_in[5];
    const float* pb  = (const float*)d_in[6];
    const float* W1  = (const float*)d_in[7];
    const float* b1  = (const float*)d_in[8];
    const float* g1  = (const float*)d_in[9];
    const float* be1 = (const float*)d_in[10];
    const float* W2  = (const float*)d_in[11];
    const float* b2  = (const float*)d_in[12];
    const float* g2  = (const float*)d_in[13];
    const float* be2 = (const float*)d_in[14];
    float* out = (float*)d_out;

    float* ws = (float*)d_ws;
    unsigned short* Kb16 = (unsigned short*)(ws + KB_OFF);
    unsigned short* Ebf  = (unsigned short*)(ws + X_OFF);    // layer-2 output
    unsigned short* Hbf  = (unsigned short*)(ws + H_OFF);
    float* norms = ws + NORM_OFF;
    float* u     = ws + U_OFF;    // colsum staging
    float* v     = ws + V_OFF;
    int* argA    = (int*)(ws + ARGA_OFF);
    int* argB    = (int*)(ws + ARGB_OFF);
    float* acc   = ws + ACC_OFF;
    unsigned short* Wt1 = (unsigned short*)(ws + WT1_OFF);
    unsigned short* Wt2 = (unsigned short*)(ws + WT2_OFF);

    zero_acc_kernel<<<128, 256, 0, stream>>>(acc, u);        // zero acc + colsum
    argmax_pa_kernel<<<128, 256, 0, stream>>>(la, lb, pa, argA, argB, acc);

    // weight transpose-casts (tiny)
    cast_wt_kernel<<<dim3(16, 16), 256, 0, stream>>>(W1, Wt1);
    cast_wt_kernel<<<dim3(16, 16), 256, 0, stream>>>(W2, Wt2);

    // fused layer 1 (f32 input, in-register cast) and layer 2 (bf16 input)
    gemmln_kernel<<<256, 512, 0, stream>>>(xA, xB, nullptr, Wt1, b1, g1, be1, Hbf, nullptr);
    gemmln_kernel<<<256, 512, 0, stream>>>(nullptr, nullptr, Hbf, Wt2, b2, g2, be2, Ebf, norms);

    // cost + K (bf16) + column sums: 512 panel blocks x 512 threads, 2 blocks/CU
    cost_mfma_kernel<<<512, 512, 0, stream>>>(Ebf, norms, argA, argB, pa, pb,
                                              Kb16, acc, u);

    // sinkhorn: 9 fused K-passes (pass-0 in cost, final u-pass in sup)
    sinkhorn_kernel<<<64, 1024, 0, stream>>>(Kb16, u, v);

    sup_kernel<<<4096, 256, 0, stream>>>(Kb16, v, rel, pa, acc);
    final_kernel<<<1, 256, 0, stream>>>(acc, out);
}